// Round 9
// baseline (424.302 us; speedup 1.0000x reference)
//
#include <hip/hip_runtime.h>
#include <math.h>

#define B_ 4
#define S_ 1024
#define D_ 1024
#define H_ 16
#define HD_ 64
#define BSD_ (B_*S_*D_)

using short8 = __attribute__((ext_vector_type(8))) short;
using f32x4  = __attribute__((ext_vector_type(4))) float;

#define MFMA16(a,b,c) __builtin_amdgcn_mfma_f32_16x16x32_bf16((a),(b),(c),0,0,0)

// ---------------- bf16 helpers (RNE) ----------------
__device__ __forceinline__ ushort f2bf(float f) {
  uint u = __float_as_uint(f);
  return (ushort)((u + 0x7fffu + ((u >> 16) & 1u)) >> 16);
}
__device__ __forceinline__ float bf2f(ushort h) {
  return __uint_as_float(((uint)h) << 16);
}
__device__ __forceinline__ void split8(const float* p, short8* hi, short8* lo) {
  #pragma unroll
  for (int j = 0; j < 8; j++) {
    ushort h = f2bf(p[j]);
    (*hi)[j] = (short)h;
    (*lo)[j] = (short)f2bf(p[j] - bf2f(h));
  }
}
// async global->LDS, 16B per lane; LDS dest = wave-uniform base + lane*16
__device__ __forceinline__ void async_load16(const ushort* g, ushort* l) {
  __builtin_amdgcn_global_load_lds(
      (const __attribute__((address_space(1))) unsigned int*)g,
      (__attribute__((address_space(3))) unsigned int*)l, 16, 0, 0);
}

// ---------------- block reduce (256 threads = 4 waves) ----------------
__device__ __forceinline__ float block_reduce_sum_256(float v, float* sbuf) {
  #pragma unroll
  for (int off = 32; off > 0; off >>= 1) v += __shfl_xor(v, off, 64);
  int lane = threadIdx.x & 63, wid = threadIdx.x >> 6;
  __syncthreads();
  if (lane == 0) sbuf[wid] = v;
  __syncthreads();
  return sbuf[0] + sbuf[1] + sbuf[2] + sbuf[3];
}

__device__ __forceinline__ void split4_store(const float4 a, ushort* orow, int c, int stride) {
  ushort4 hi, lo;
  hi.x = f2bf(a.x); hi.y = f2bf(a.y); hi.z = f2bf(a.z); hi.w = f2bf(a.w);
  lo.x = f2bf(a.x - bf2f(hi.x)); lo.y = f2bf(a.y - bf2f(hi.y));
  lo.z = f2bf(a.z - bf2f(hi.z)); lo.w = f2bf(a.w - bf2f(hi.w));
  *(ushort4*)(orow + c)          = hi;
  *(ushort4*)(orow + stride + c) = lo;
}

// ---------------- fused prep: all input-side transforms in ONE dispatch ----------
__global__ __launch_bounds__(256) void prep_kernel(
    const float* __restrict__ x,
    const float* __restrict__ ln_a_g, const float* __restrict__ ln_a_b,
    const float* __restrict__ ln_b_g, const float* __restrict__ ln_b_b,
    const float* __restrict__ Wq, const float* __restrict__ Wk,
    const float* __restrict__ Wv, const float* __restrict__ bq,
    const float* __restrict__ bv, const float* __restrict__ Wo,
    const float* __restrict__ Wproj,
    ushort* __restrict__ Acat, ushort* __restrict__ Bqkv,
    float* __restrict__ biascat, float* __restrict__ loc,
    ushort* __restrict__ B3, ushort* __restrict__ Bo) {
  __shared__ float sbuf[4];
  const int bx = blockIdx.x;
  const int t = threadIdx.x;
  if (bx < 4096) {
    const int row = bx;
    const int c = t*4;
    const float* xr = x + (size_t)row * D_;
    float4 v = *(const float4*)(xr + c);
    float s = v.x + v.y + v.z + v.w;
    const float mean = block_reduce_sum_256(s, sbuf) * (1.0f/D_);
    float4 dv = make_float4(v.x-mean, v.y-mean, v.z-mean, v.w-mean);
    float sq = dv.x*dv.x + dv.y*dv.y + dv.z*dv.z + dv.w*dv.w;
    const float var = block_reduce_sum_256(sq, sbuf) * (1.0f/D_);
    const float r = rsqrtf(var + 1e-5f);
    float4 gg = *(const float4*)(ln_b_g + c);
    float4 bb = *(const float4*)(ln_b_b + c);
    float4 n;
    n.x = dv.x*r*gg.x + bb.x; n.y = dv.y*r*gg.y + bb.y;
    n.z = dv.z*r*gg.z + bb.z; n.w = dv.w*r*gg.w + bb.w;
    split4_store(n, Acat + (size_t)row*2048, c, 1024);
  } else if (bx < 7168) {
    const int idx = (bx - 4096)*256 + t;
    const int n = idx >> 8;
    const int col4 = (idx & 255) << 2;
    const float* src = (n < 1024) ? (Wq + (size_t)n*1024)
                     : (n < 2048) ? (Wk + (size_t)(n-1024)*1024)
                                  : (Wv + (size_t)(n-2048)*1024);
    const float4 a = *(const float4*)(src + col4);
    split4_store(a, Bqkv + (size_t)n*2048, col4, 1024);
    if (idx < 3072)
      biascat[idx] = (idx < 1024) ? bq[idx] : (idx < 2048) ? 0.f : bv[idx-2048];
  } else if (bx < 11264) {
    const int row = bx - 7168;
    const float* xr = x + (size_t)row * D_;
    float v[4]; float s = 0.f;
    #pragma unroll
    for (int i = 0; i < 4; i++) { v[i] = xr[t + 256*i]; s += v[i]; }
    const float mean = block_reduce_sum_256(s, sbuf) * (1.0f/D_);
    float sq = 0.f;
    #pragma unroll
    for (int i = 0; i < 4; i++) { float d = v[i]-mean; sq += d*d; }
    const float var = block_reduce_sum_256(sq, sbuf) * (1.0f/D_);
    const float r = rsqrtf(var + 1e-5f);
    float* orow = loc + (size_t)row * D_;
    #pragma unroll
    for (int i = 0; i < 4; i++) {
      int c = t + 256*i;
      orow[c] = (v[i]-mean)*r*ln_a_g[c] + ln_a_b[c];
    }
  } else if (bx < 13312) {
    const int idx = (bx - 11264)*256 + t;
    const int row = idx >> 9;
    const int col4 = (idx & 511) << 2;
    const float4 a = *(const float4*)(Wproj + (size_t)row*2048 + col4);
    ushort4 hi;
    hi.x = f2bf(a.x); hi.y = f2bf(a.y); hi.z = f2bf(a.z); hi.w = f2bf(a.w);
    *(ushort4*)(B3 + (size_t)row*2048 + col4) = hi;
  } else {
    const int idx = (bx - 13312)*256 + t;
    const int n = idx >> 8;
    const int col4 = (idx & 255) << 2;
    const float4 a = *(const float4*)(Wo + (size_t)n*1024 + col4);
    split4_store(a, Bo + (size_t)n*2048, col4, 1024);
  }
}

// =====================================================================
// 128x128 pipelined QKV GEMM: 768 blocks, 4 waves, 64KB LDS double-buffer.
// R9: single-sync K-groups — within a group all waves only READ slot t
// (read-only, no inter-wave hazard) and WRITE slot t+1 (disjoint), so the
// only required sync per K-step is {per-wave vmcnt(0); s_barrier} at group
// end: guarantees (a) all waves' t+1 loads retired before any wave reads
// slot t+1 next group; (b) stage(t+2)->slot(t) follows all reads of t
// (reads consumed into VGPRs via lgkmcnt before the barrier).
// Barriers/K-step: 8 -> 1. MFMA order & staging bytes bit-identical.
// =====================================================================
#define BARRIER() asm volatile("s_barrier" ::: "memory")
#define VMW(n)  asm volatile("s_waitcnt vmcnt(" #n ")" ::: "memory")

// Burst-issue all 8 loads/wave for K-step k0 into slot SBs.
// cid = wave*2+i in 0..7: hl = cid>>2 (hi/lo panel), rs = cid&3 (16-row seg).
#define STAGE4(k0, SBs) do { \
  _Pragma("unroll") \
  for (int i_ = 0; i_ < 2; ++i_) { \
    const int cid_ = wave*2 + i_, hl_ = cid_>>2, rs_ = cid_&3; \
    const int r0_ = (rs_>>1)*64 + (rs_&1)*16; \
    async_load16(A  + ((size_t)(bm + r0_ + lrow) << 11) + (hl_ << 10) + (k0) + sw, \
                 (SBs) + hl_*4096 + r0_*32); \
  } \
  _Pragma("unroll") \
  for (int i_ = 0; i_ < 2; ++i_) { \
    const int cid_ = wave*2 + i_, hl_ = cid_>>2, rs_ = cid_&3; \
    const int r0_ = (rs_>>1)*64 + (rs_&1)*16; \
    async_load16(Bw + ((size_t)(bn + r0_ + lrow) << 11) + (hl_ << 10) + (k0) + sw, \
                 (SBs) + 8192 + hl_*4096 + r0_*32); \
  } \
  _Pragma("unroll") \
  for (int i_ = 0; i_ < 2; ++i_) { \
    const int cid_ = wave*2 + i_, hl_ = cid_>>2, rs_ = cid_&3; \
    const int r1_ = (rs_>>1)*64 + (rs_&1)*16 + 32; \
    async_load16(Bw + ((size_t)(bn + r1_ + lrow) << 11) + (hl_ << 10) + (k0) + sw, \
                 (SBs) + 8192 + hl_*4096 + r1_*32); \
  } \
  _Pragma("unroll") \
  for (int i_ = 0; i_ < 2; ++i_) { \
    const int cid_ = wave*2 + i_, hl_ = cid_>>2, rs_ = cid_&3; \
    const int r1_ = (rs_>>1)*64 + (rs_&1)*16 + 32; \
    async_load16(A  + ((size_t)(bm + r1_ + lrow) << 11) + (hl_ << 10) + (k0) + sw, \
                 (SBs) + hl_*4096 + r1_*32); \
  } \
} while (0)

// One phase: quadrant (mh,nh). No barriers; slot t is read-only this group.
#define PH4(mh, nh, SBc, STG) do { \
  short8 ah_[2], al_[2], bh_[2], bl_[2]; \
  _Pragma("unroll") \
  for (int m4_ = 0; m4_ < 2; ++m4_) { \
    const int ro_ = (wm*64 + (mh)*32 + m4_*16 + lm)*32 + rsw; \
    ah_[m4_] = *(const short8*)&(SBc)[ro_]; \
    al_[m4_] = *(const short8*)&(SBc)[4096 + ro_]; } \
  _Pragma("unroll") \
  for (int n2_ = 0; n2_ < 2; ++n2_) { \
    const int ro_ = (wn*64 + (nh)*32 + n2_*16 + lm)*32 + rsw; \
    bh_[n2_] = *(const short8*)&(SBc)[8192 + ro_]; \
    bl_[n2_] = *(const short8*)&(SBc)[12288 + ro_]; } \
  STG; \
  __builtin_amdgcn_s_setprio(1); \
  _Pragma("unroll") \
  for (int m4_ = 0; m4_ < 2; ++m4_) \
    _Pragma("unroll") \
    for (int n2_ = 0; n2_ < 2; ++n2_) { \
      f32x4 t_ = acc[(mh)*2+m4_][(nh)*2+n2_]; \
      t_ = MFMA16(ah_[m4_], bh_[n2_], t_); \
      t_ = MFMA16(al_[m4_], bh_[n2_], t_); \
      t_ = MFMA16(ah_[m4_], bl_[n2_], t_); \
      acc[(mh)*2+m4_][(nh)*2+n2_] = t_; } \
  __builtin_amdgcn_s_setprio(0); \
} while (0)

// K-group g: compute tile t=g from SBc, burst-stage tile t+1 into SBs at P0.
// Single group-end sync (see header comment).
#define GROUP4(g, SBc, SBs) do { \
  const int k0n_ = (((g) + 1) & 31) * 32; \
  PH4(0, 0, (SBc), STAGE4(k0n_, (SBs))); \
  PH4(0, 1, (SBc), ((void)0)); \
  PH4(1, 0, (SBc), ((void)0)); \
  PH4(1, 1, (SBc), ((void)0)); \
  VMW(0); \
  BARRIER(); \
} while (0)

__global__ __launch_bounds__(256, 2) void qkv4_kernel(
    const ushort* __restrict__ A, const ushort* __restrict__ Bw,
    const float* __restrict__ bias,
    ushort* __restrict__ Qsp, ushort* __restrict__ Ksp,
    ushort* __restrict__ Vth, ushort* __restrict__ Vtl) {
  extern __shared__ __align__(16) ushort smem[];   // 2 slots x 32KB
  const int tid = threadIdx.x;
  const int bm = blockIdx.y * 128, bn = blockIdx.x * 128;
  const int wave = tid >> 6, lane = tid & 63;
  const int wm = wave >> 1, wn = wave & 1;
  const int lm = lane & 15, q = lane >> 4;
  const int lrow = lane >> 2;
  const int sw = (((lane & 3) ^ ((lane >> 3) & 3)) << 3);
  const int rsw = ((q ^ ((lm >> 1) & 3)) << 3);

  f32x4 acc[4][4];
  #pragma unroll
  for (int i = 0; i < 4; i++)
    #pragma unroll
    for (int j = 0; j < 4; j++)
      acc[i][j] = (f32x4){0.f,0.f,0.f,0.f};

  // prologue: stage tile 0 into slot0; full drain once
  STAGE4(0, smem);
  VMW(0); BARRIER();

  #pragma unroll 1
  for (int g = 0; g < 32; g += 2) {
    GROUP4(g,     smem,         smem + 16384);
    GROUP4(g + 1, smem + 16384, smem);
  }
  VMW(0);
  __syncthreads();

  // -------- epilogue identical to the proven 128x128 kernel --------
  const int b = bm >> 10, s0 = bm & 1023;
  if (blockIdx.x < 16) {
    ushort* dst = (blockIdx.x < 8) ? Qsp : Ksp;
    #pragma unroll
    for (int mt = 0; mt < 4; mt++) {
      #pragma unroll
      for (int nt = 0; nt < 4; nt++) {
        const int n = bn + wn*64 + nt*16 + lm;
        const int h = (n >> 6) & 15;
        const int d = nt*16 + lm;
        const float bb = bias[n];
        #pragma unroll
        for (int reg = 0; reg < 4; reg++) {
          const int s = s0 + wm*64 + mt*16 + q*4 + reg;
          const float val = acc[mt][nt][reg] + bb;
          const ushort hi = f2bf(val);
          const ushort lo = f2bf(val - bf2f(hi));
          ushort* rp = dst + ((size_t)((b*16 + h)*1024 + s))*128;
          rp[d] = hi; rp[64 + d] = lo;
        }
      }
    }
  } else {
    ushort* Th = smem;            // [64][136] ushorts
    ushort* Tl = smem + 8704;
    #pragma unroll
    for (int c = 0; c < 2; c++) {
      __syncthreads();
      if (wn == c) {
        #pragma unroll
        for (int mt = 0; mt < 4; mt++)
          #pragma unroll
          for (int nt = 0; nt < 4; nt++) {
            const int nl = nt*16 + lm;
            const float bb = bias[bn + c*64 + nl];
            #pragma unroll
            for (int reg = 0; reg < 4; reg++) {
              const int sl = wm*64 + mt*16 + q*4 + reg;
              const float val = acc[mt][nt][reg] + bb;
              const ushort hi = f2bf(val);
              const ushort lo = f2bf(val - bf2f(hi));
              Th[nl*136 + sl] = hi;
              Tl[nl*136 + sl] = lo;
            }
          }
      }
      __syncthreads();
      const int nl = tid >> 2, s32 = (tid & 3)*32;
      const int h = ((bn - 2048 + c*64) >> 6) & 15;
      const size_t drow = ((size_t)((b*16 + h)*64 + nl))*1024 + s0 + s32;
      #pragma unroll
      for (int j = 0; j < 4; j++) {
        *(short8*)(Vth + drow + j*8) = *(const short8*)&Th[nl*136 + s32 + j*8];
        *(short8*)(Vtl + drow + j*8) = *(const short8*)&Tl[nl*136 + s32 + j*8];
      }
    }
  }
}

// ---------------- QKV GEMM fallback (old 128x128, 768 blocks) -------
__global__ __launch_bounds__(256) void mfma_gemm_qkv(
    const ushort* __restrict__ A, const ushort* __restrict__ Bw,
    const float* __restrict__ bias,
    ushort* __restrict__ Qsp, ushort* __restrict__ Ksp,
    ushort* __restrict__ Vth, ushort* __restrict__ Vtl, int Kh) {
  __shared__ __align__(16) ushort smem[17408];
  ushort* Ash = smem;
  ushort* Asl = smem + 4096;
  ushort* Bsh = smem + 8192;
  ushort* Bsl = smem + 12288;
  const int lda = 2*Kh;
  const int tid = threadIdx.x;
  const int bm = blockIdx.y * 128, bn = blockIdx.x * 128;
  const int wave = tid >> 6, lane = tid & 63;
  const int wm = wave >> 1, wn = wave & 1;
  const int lm = lane & 15, q = lane >> 4;
  const int lrow = lane >> 2;
  const int sw = (((lane & 3) ^ ((lane >> 3) & 3)) << 3);

  f32x4 acc[4][4];
  #pragma unroll
  for (int i = 0; i < 4; i++)
    #pragma unroll
    for (int j = 0; j < 4; j++)
      acc[i][j] = (f32x4){0.f,0.f,0.f,0.f};

  const ushort* Agh = A  + (size_t)(bm + wave*32 + lrow)*lda + sw;
  const ushort* Agl = Agh + Kh;
  const ushort* Bgh = Bw + (size_t)(bn + wave*32 + lrow)*lda + sw;
  const ushort* Bgl = Bgh + Kh;
  const size_t r16a = (size_t)16*lda;
  ushort* AhD0 = &Ash[(wave*32)*32];      ushort* AhD1 = &Ash[(wave*32+16)*32];
  ushort* AlD0 = &Asl[(wave*32)*32];      ushort* AlD1 = &Asl[(wave*32+16)*32];
  ushort* BhD0 = &Bsh[(wave*32)*32];      ushort* BhD1 = &Bsh[(wave*32+16)*32];
  ushort* BlD0 = &Bsl[(wave*32)*32];      ushort* BlD1 = &Bsl[(wave*32+16)*32];
  const int rsw  = ((q ^ ((lm >> 1) & 3)) << 3);
  const int aoff = (wm*64 + lm)*32 + rsw;
  const int boff = (wn*64 + lm)*32 + rsw;

  for (int k0 = 0; k0 < Kh; k0 += 32) {
    __syncthreads();
    async_load16(Agh + k0, AhD0);
    async_load16(Agh + r16a + k0, AhD1);
    async_load16(Agl + k0, AlD0);
    async_load16(Agl + r16a + k0, AlD1);
    async_load16(Bgh + k0, BhD0);
    async_load16(Bgh + r16a + k0, BhD1);
    async_load16(Bgl + k0, BlD0);
    async_load16(Bgl + r16a + k0, BlD1);
    __syncthreads();
    short8 ah[4], al[4], bh[4], bl[4];
    #pragma unroll
    for (int mt = 0; mt < 4; mt++) {
      ah[mt] = *(const short8*)&Ash[aoff + mt*512];
      al[mt] = *(const short8*)&Asl[aoff + mt*512];
    }
    #pragma unroll
    for (int nt = 0; nt < 4; nt++) {
      bh[nt] = *(const short8*)&Bsh[boff + nt*512];
      bl[nt] = *(const short8*)&Bsl[boff + nt*512];
    }
    #pragma unroll
    for (int mt = 0; mt < 4; mt++)
      #pragma unroll
      for (int nt = 0; nt < 4; nt++) {
        f32x4 a = acc[mt][nt];
        a = MFMA16(ah[mt], bh[nt], a);
        a = MFMA16(al[mt], bh[nt], a);
        a = MFMA16(ah[mt], bl[nt], a);
        acc[mt][nt] = a;
      }
  }

  const int b = bm >> 10, s0 = bm & 1023;
  if (blockIdx.x < 16) {
    ushort* dst = (blockIdx.x < 8) ? Qsp : Ksp;
    #pragma unroll
    for (int mt = 0; mt < 4; mt++) {
      #pragma unroll
      for (int nt = 0; nt < 4; nt++) {
        const int n = bn + wn*64 + nt*16 + lm;
        const int h = (n >> 6) & 15;
        const int d = nt*16 + lm;
        const float bb = bias[n];
        #pragma unroll
        for (int reg = 0; reg < 4; reg++) {
          const int s = s0 + wm*64 + mt*16 + q*4 + reg;
          const float val = acc[mt][nt][reg] + bb;
          const ushort hi = f2bf(val);
          const ushort lo = f2bf(val - bf2f(hi));
          ushort* rp = dst + ((size_t)((b*16 + h)*1024 + s))*128;
          rp[d] = hi; rp[64 + d] = lo;
        }
      }
    }
  } else {
    ushort* Th = smem;
    ushort* Tl = smem + 8704;
    #pragma unroll
    for (int c = 0; c < 2; c++) {
      __syncthreads();
      if (wn == c) {
        #pragma unroll
        for (int mt = 0; mt < 4; mt++)
          #pragma unroll
          for (int nt = 0; nt < 4; nt++) {
            const int nl = nt*16 + lm;
            const float bb = bias[bn + c*64 + nl];
            #pragma unroll
            for (int reg = 0; reg < 4; reg++) {
              const int sl = wm*64 + mt*16 + q*4 + reg;
              const float val = acc[mt][nt][reg] + bb;
              const ushort hi = f2bf(val);
              const ushort lo = f2bf(val - bf2f(hi));
              Th[nl*136 + sl] = hi;
              Tl[nl*136 + sl] = lo;
            }
          }
      }
      __syncthreads();
      const int nl = tid >> 2, s32 = (tid & 3)*32;
      const int h = ((bn - 2048 + c*64) >> 6) & 15;
      const size_t drow = ((size_t)((b*16 + h)*64 + nl))*1024 + s0 + s32;
      #pragma unroll
      for (int j = 0; j < 4; j++) {
        *(short8*)(Vth + drow + j*8) = *(const short8*)&Th[nl*136 + s32 + j*8];
        *(short8*)(Vtl + drow + j*8) = *(const short8*)&Tl[nl*136 + s32 + j*8];
      }
    }
  }
}

// ------- dual-panel bf16x3 MFMA GEMM, 64x128 tile (512 blocks = 2/CU) ------------
__global__ __launch_bounds__(256) void mfma_gemm2(
    const ushort* __restrict__ A, const ushort* __restrict__ Bw,
    const float* __restrict__ bias, float* __restrict__ C,
    int Kh, int ldc, ushort* __restrict__ aux) {
  __shared__ __align__(16) ushort Ash[64*32];
  __shared__ __align__(16) ushort Asl[64*32];
  __shared__ __align__(16) ushort Bsh[128*32];
  __shared__ __align__(16) ushort Bsl[128*32];
  const int lda = 2*Kh;
  const int tid = threadIdx.x;
  const int bm = blockIdx.y * 64, bn = blockIdx.x * 128;
  const int wave = tid >> 6, lane = tid & 63;
  const int lm = lane & 15, q = lane >> 4;
  const int lrow = lane >> 2;
  const int sw = (((lane & 3) ^ ((lane >> 3) & 3)) << 3);

  f32x4 acc[4][2];
  #pragma unroll
  for (int i = 0; i < 4; i++)
    #pragma unroll
    for (int j = 0; j < 2; j++)
      acc[i][j] = (f32x4){0.f,0.f,0.f,0.f};

  const ushort* gsrc[6];
  ushort* ldst[6];
  #pragma unroll
  for (int i = 0; i < 6; i++) {
    const int s = wave*6 + i;
    const ushort* gp; ushort* lp;
    if (s < 4)       { gp = A  + (size_t)(bm + s*16 + lrow)*lda + sw;           lp = &Ash[(s*16)*32]; }
    else if (s < 8)  { gp = A  + (size_t)(bm + (s-4)*16 + lrow)*lda + Kh + sw;  lp = &Asl[((s-4)*16)*32]; }
    else if (s < 16) { gp = Bw + (size_t)(bn + (s-8)*16 + lrow)*lda + sw;       lp = &Bsh[((s-8)*16)*32]; }
    else             { gp = Bw + (size_t)(bn + (s-16)*16 + lrow)*lda + Kh + sw; lp = &Bsl[((s-16)*16)*32]; }
    gsrc[i] = gp; ldst[i] = lp;
  }
  const int rsw = ((q ^ ((lm >> 1) & 3)) << 3);
  const int aoff = lm*32 + rsw;
  const int boff = (wave*32 + lm)*32 + rsw;

  for (int k0 = 0; k0 < Kh; k0 += 32) {
    __syncthreads();
    #pragma unroll
    for (int i = 0; i < 6; i++) async_load16(gsrc[i] + k0, ldst[i]);
    __syncthreads();
    short8 ah[4], al[4], bh[2], bl[2];
    #pragma unroll
    for (int mt = 0; mt < 4; mt++) {
      ah[mt] = *(const short8*)&Ash[aoff + mt*512];
      al[mt] = *(const short8*)&Asl[aoff + mt*512];
    }
    #pragma unroll
    for (int nt = 0; nt < 2; nt++) {
      bh[nt] = *(const short8*)&Bsh[boff + nt*512];
      bl[nt] = *(const short8*)&Bsl[boff + nt*512];
    }
    #pragma unroll
    for (int mt = 0; mt < 4; mt++)
      #pragma unroll
      for (int nt = 0; nt < 2; nt++) {
        f32x4 a = acc[mt][nt];
        a = MFMA16(ah[mt], bh[nt], a);
        a = MFMA16(al[mt], bh[nt], a);
        a = MFMA16(ah[mt], bl[nt], a);
        acc[mt][nt] = a;
      }
  }

  #pragma unroll
  for (int mt = 0; mt < 4; mt++) {
    #pragma unroll
    for (int nt = 0; nt < 2; nt++) {
      const int n = bn + wave*32 + nt*16 + lm;
      const float bb = bias ? bias[n] : 0.f;
      #pragma unroll
      for (int reg = 0; reg < 4; reg++) {
        const int m = bm + mt*16 + q*4 + reg;
        const float val = acc[mt][nt][reg] + bb;
        C[(size_t)m*ldc + n] = val;
        if (aux) aux[(size_t)m*2048 + 1024 + n] = f2bf(val);
      }
    }
  }
}

// ---------- plain bf16 MFMA GEMM, 64x128 tile (512 blocks = 2/CU) ----------------
__global__ __launch_bounds__(256) void mfma_gemm(
    const ushort* __restrict__ A, const ushort* __restrict__ Bw,
    const float* __restrict__ bias, float* __restrict__ C,
    int K, int ldc) {
  __shared__ __align__(16) ushort As[64*32];
  __shared__ __align__(16) ushort Bs[128*32];
  const int tid = threadIdx.x;
  const int bm = blockIdx.y * 64, bn = blockIdx.x * 128;
  const int wave = tid >> 6, lane = tid & 63;
  const int lm = lane & 15, q = lane >> 4;
  const int lrow = lane >> 2;
  const int sw = (((lane & 3) ^ ((lane >> 3) & 3)) << 3);

  f32x4 acc[4][2];
  #pragma unroll
  for (int i = 0; i < 4; i++)
    #pragma unroll
    for (int j = 0; j < 2; j++)
      acc[i][j] = (f32x4){0.f,0.f,0.f,0.f};

  const ushort* gsrc[3];
  ushort* ldst[3];
  #pragma unroll
  for (int i = 0; i < 3; i++) {
    const int s = wave*3 + i;
    const ushort* gp; ushort* lp;
    if (s < 4) { gp = A  + (size_t)(bm + s*16 + lrow)*K + sw;     lp = &As[(s*16)*32]; }
    else       { gp = Bw + (size_t)(bn + (s-4)*16 + lrow)*K + sw; lp = &Bs[((s-4)*16)*32]; }
    gsrc[i] = gp; ldst[i] = lp;
  }
  const int rsw = ((q ^ ((lm >> 1) & 3)) << 3);
  const int aoff = lm*32 + rsw;
  const int boff = (wave*32 + lm)*32 + rsw;

  for (int k0 = 0; k0 < K; k0 += 32) {
    __syncthreads();
    #pragma unroll
    for (int i = 0; i < 3; i++) async_load16(gsrc[i] + k0, ldst[i]);
    __syncthreads();
    short8 af[4], bf[2];
    #pragma unroll
    for (int mt = 0; mt < 4; mt++) af[mt] = *(const short8*)&As[aoff + mt*512];
    #pragma unroll
    for (int nt = 0; nt < 2; nt++) bf[nt] = *(const short8*)&Bs[boff + nt*512];
    #pragma unroll
    for (int mt = 0; mt < 4; mt++)
      #pragma unroll
      for (int nt = 0; nt < 2; nt++)
        acc[mt][nt] = MFMA16(af[mt], bf[nt], acc[mt][nt]);
  }

  #pragma unroll
  for (int mt = 0; mt < 4; mt++) {
    #pragma unroll
    for (int nt = 0; nt < 2; nt++) {
      const int n = bn + wave*32 + nt*16 + lm;
      const float bb = bias ? bias[n] : 0.f;
      #pragma unroll
      for (int reg = 0; reg < 4; reg++) {
        const int m = bm + mt*16 + q*4 + reg;
        C[(size_t)m*ldc + n] = acc[mt][nt][reg] + bb;
      }
    }
  }
}

// ---- one q-tile x k-tile attention unit (scores -> softmax -> PV) ----
// T5: setprio(1) around both MFMA clusters (R8 win).
__device__ __forceinline__ void attn_unit(
    int qt, int kt, int w, int lm, int q,
    const short8 qh[2], const short8 ql[2],
    const ushort* Kc, const ushort* Vc, float* Pf,
    f32x4 of[4], float mst[4], float lst[4]) {
  f32x4 sS[4];
  __builtin_amdgcn_s_setprio(1);
  #pragma unroll
  for (int nt = 0; nt < 4; nt++) {
    const ushort* kr = &Kc[(nt*16 + lm)*136 + q*8];
    const short8 kh0 = *(const short8*)(kr);
    const short8 kh1 = *(const short8*)(kr + 32);
    const short8 kl0 = *(const short8*)(kr + 64);
    const short8 kl1 = *(const short8*)(kr + 96);
    f32x4 a = (f32x4){0.f,0.f,0.f,0.f};
    a = MFMA16(qh[0], kh0, a);
    a = MFMA16(ql[0], kh0, a);
    a = MFMA16(qh[0], kl0, a);
    a = MFMA16(qh[1], kh1, a);
    a = MFMA16(ql[1], kh1, a);
    a = MFMA16(qh[1], kl1, a);
    sS[nt] = a;
  }
  __builtin_amdgcn_s_setprio(0);
  const int ktbase = kt*64;
  const int qrow0 = qt*64 + w*16 + q*4;
  #pragma unroll
  for (int rm = 0; rm < 4; rm++) {
    const int qrow = qrow0 + rm;
    float v[4];
    #pragma unroll
    for (int nt = 0; nt < 4; nt++) {
      const int kcol = ktbase + nt*16 + lm;
      const float x = sS[nt][rm]*0.125f;
      v[nt] = (kcol <= qrow) ? x : -INFINITY;
    }
    float tm = fmaxf(fmaxf(v[0],v[1]), fmaxf(v[2],v[3]));
    #pragma unroll
    for (int off = 1; off < 16; off <<= 1) tm = fmaxf(tm, __shfl_xor(tm, off, 64));
    const float nm = fmaxf(mst[rm], tm);
    const float alpha = __expf(mst[rm] - nm);
    float ps = 0.f;
    #pragma unroll
    for (int nt = 0; nt < 4; nt++) {
      float p = __expf(v[nt] - nm);
      sS[nt][rm] = p;
      ps += p;
    }
    #pragma unroll
    for (int off = 1; off < 16; off <<= 1) ps += __shfl_xor(ps, off, 64);
    lst[rm] = lst[rm]*alpha + ps;
    mst[rm] = nm;
    #pragma unroll
    for (int nt = 0; nt < 4; nt++) of[nt][rm] *= alpha;
  }
  #pragma unroll
  for (int rm = 0; rm < 4; rm++)
    #pragma unroll
    for (int nt = 0; nt < 4; nt++)
      Pf[(w*16 + q*4 + rm)*66 + nt*16 + lm] = sS[nt][rm];
  short8 ph[2], pl[2];
  {
    const float* prow = &Pf[(w*16 + lm)*66];
    float pv[16];
    *(float4*)&pv[0]  = *(const float4*)(prow + q*8);
    *(float4*)&pv[4]  = *(const float4*)(prow + q*8 + 4);
    *(float4*)&pv[8]  = *(const float4*)(prow + 32 + q*8);
    *(float4*)&pv[12] = *(const float4*)(prow + 32 + q*8 + 4);
    split8(&pv[0], &ph[0], &pl[0]);
    split8(&pv[8], &ph[1], &pl[1]);
  }
  __builtin_amdgcn_s_setprio(1);
  #pragma unroll
  for (int nt = 0; nt < 4; nt++) {
    const ushort* vr = &Vc[(nt*16 + lm)*136 + q*8];
    const short8 vh0 = *(const short8*)(vr);
    const short8 vh1 = *(const short8*)(vr + 32);
    const short8 vl0 = *(const short8*)(vr + 64);
    const short8 vl1 = *(const short8*)(vr + 96);
    f32x4 a = of[nt];
    a = MFMA16(ph[0], vh0, a);
    a = MFMA16(pl[0], vh0, a);
    a = MFMA16(ph[0], vl0, a);
    a = MFMA16(ph[1], vh1, a);
    a = MFMA16(pl[1], vh1, a);
    a = MFMA16(ph[1], vl1, a);
    of[nt] = a;
  }
  __builtin_amdgcn_s_setprio(0);
}

// ---- MFMA causal flash attention: dual q-tile, shared K/V staging ----
// XCD-aware epoch balancing (R7 win): per-CU epoch sum = 25, constant.
__global__ __launch_bounds__(256) void gattn_mfma(
    const ushort* __restrict__ Qsp, const ushort* __restrict__ Ksp,
    const ushort* __restrict__ Vth, const ushort* __restrict__ Vtl,
    ushort* __restrict__ Aout) {
  __shared__ __align__(16) ushort Kc[64*136];
  __shared__ __align__(16) ushort Vc[64*136];
  __shared__ __align__(16) float  Pf[64*66];
  const int bh = blockIdx.y;
  const int b = bh >> 4, h = bh & 15;
  const int tid = threadIdx.x;
  const int w = tid >> 6, lane = tid & 63;
  const int lm = lane & 15, q = lane >> 4;
  const ushort* Qb_ = Qsp + (size_t)bh * (1024*128);
  const ushort* Kb_ = Ksp + (size_t)bh * (1024*128);
  const ushort* Vhb = Vth + (size_t)bh * (64*1024);
  const ushort* Vlb = Vtl + (size_t)bh * (64*1024);
  const int half = (bh >> 5) & 1;
  const int qtA = half ? (8 + (int)blockIdx.x) : (15 - (int)blockIdx.x);
  const int qtB = half ? (7 - (int)blockIdx.x) : (int)blockIdx.x;

  short8 qhA[2], qlA[2], qhB[2], qlB[2];
  {
    const ushort* qr = Qb_ + (size_t)(qtA*64 + w*16 + lm)*128 + q*8;
    qhA[0] = *(const short8*)(qr);
    qhA[1] = *(const short8*)(qr + 32);
    qlA[0] = *(const short8*)(qr + 64);
    qlA[1] = *(const short8*)(qr + 96);
    const ushort* qr2 = Qb_ + (size_t)(qtB*64 + w*16 + lm)*128 + q*8;
    qhB[0] = *(const short8*)(qr2);
    qhB[1] = *(const short8*)(qr2 + 32);
    qlB[0] = *(const short8*)(qr2 + 64);
    qlB[1] = *(const short8*)(qr2 + 96);
  }
  f32x4 ofA[4], ofB[4];
  float mstA[4], lstA[4], mstB[4], lstB[4];
  #pragma unroll
  for (int nt = 0; nt < 4; nt++) {
    ofA[nt] = (f32x4){0.f,0.f,0.f,0.f};
    ofB[nt] = (f32x4){0.f,0.f,0.f,0.f};
  }
  #pragma unroll
  for (int rm = 0; rm < 4; rm++) {
    mstA[rm] = -INFINITY; lstA[rm] = 0.f;
    mstB[rm] = -INFINITY; lstB[rm] = 0.f;
  }

  for (int kt = 0; kt <= qtA; ++kt) {
    __syncthreads();
    #pragma unroll
    for (int i = 0; i < 4; i++) {
      const int slot = i*256 + tid;
      const int row = slot >> 4, c8 = slot & 15;
      *(float4*)&Kc[row*136 + c8*8] =
          *(const float4*)(Kb_ + (size_t)(kt*64 + row)*128 + c8*8);
      const ushort* vsrc = ((c8 < 8) ? Vhb : Vlb) + (size_t)row*1024 + kt*64 + (c8&7)*8;
      *(float4*)&Vc[row*136 + c8*8] = *(const float4*)vsrc;
    }
    __syncthreads();
    attn_unit(qtA, kt, w, lm, q, qhA, qlA, Kc, Vc, Pf, ofA, mstA, lstA);
    if (kt <= qtB)
      attn_unit(qtB, kt, w, lm, q, qhB, qlB, Kc, Vc, Pf, ofB, mstB, lstB);
  }

  #pragma unroll
  for (int rm = 0; rm < 4; rm++) {
    const float invA = 1.0f / lstA[rm];
    const int sA = qtA*64 + w*16 + q*4 + rm;
    ushort* arow = Aout + ((size_t)(b*1024 + sA))*2048 + h*64;
    #pragma unroll
    for (int nt = 0; nt < 4; nt++) {
      const float val = ofA[nt][rm] * invA;
      const ushort hi = f2bf(val);
      arow[nt*16 + lm] = hi;
      arow[1024 + nt*16 + lm] = f2bf(val - bf2f(hi));
    }
    const float invB = 1.0f / lstB[rm];
    const int sB = qtB*64 + w*16 + q*4 + rm;
    ushort* brow = Aout + ((size_t)(b*1024 + sB))*2048 + h*64;
    #pragma unroll
    for (int nt = 0; nt < 4; nt++) {
      const float val = ofB[nt][rm] * invB;
      const ushort hi = f2bf(val);
      brow[nt*16 + lm] = hi;
      brow[1024 + nt*16 + lm] = f2bf(val - bf2f(hi));
    }
  }
}

// ---------------- seq-mean, 2-stage deterministic ----------------
__global__ __launch_bounds__(256) void seqmean1_kernel(const float* __restrict__ g,
                                                       float* __restrict__ part) {
  const int d = blockIdx.x*256 + threadIdx.x;
  const int sc = blockIdx.y;
  const int b = blockIdx.z;
  const float* p = g + ((size_t)b*S_ + sc*128)*D_ + d;
  float s = 0.f;
  #pragma unroll 4
  for (int i = 0; i < 128; i++) s += p[(size_t)i*D_];
  part[((size_t)(b*8 + sc))*D_ + d] = s;
}
__global__ __launch_bounds__(256) void seqmean2_kernel(const float* __restrict__ part,
                                                       float* __restrict__ mbd) {
  const int d = blockIdx.x*256 + threadIdx.x;
  const int b = blockIdx.y;
  float s = 0.f;
  #pragma unroll
  for (int i = 0; i < 8; i++) s += part[((size_t)(b*8 + i))*D_ + d];
  mbd[b*D_ + d] = s * (1.0f/S_);
}

// ---------------- predictor ----------------
__global__ __launch_bounds__(256) void predictor_kernel(
    const float* __restrict__ mbd, const float* __restrict__ Wp,
    const float* __restrict__ bp, float* __restrict__ fpar, int* __restrict__ ipar) {
  __shared__ float sbuf[4];
  __shared__ float sdots[4];
  const int tid = threadIdx.x;
  for (int b = 0; b < 4; b++) {
    float psum = 0.f;
    for (int d = tid; d < D_; d += 256) psum += mbd[b*D_ + d]*Wp[d];
    float tot = block_reduce_sum_256(psum, sbuf);
    if (tid == 0) sdots[b] = tot;
  }
  __syncthreads();
  if (tid == 0) {
    float smv = 0.f;
    for (int b = 0; b < 4; b++) {
      float z = sdots[b] + bp[0];
      smv += 1.0f/(1.0f + expf(-z));
    }
    smv *= 0.25f;
    int win = max(1, (int)(256.0f*smv));
    int span_len = max(1, (int)(512.0f*smv));
    int local_max = min(512, min(span_len, win));
    float temp = 1.0f + 0.01f*(1.0f - smv);
    int n_win = (S_ + win - 1)/win;
    fpar[0] = smv; fpar[1] = temp;
    ipar[0] = win; ipar[1] = span_len; ipar[2] = local_max; ipar[3] = n_win;
  }
}

// -------- dynamic sliding-window span attention (fp32 -> bf16 out, self-zeroing) --
#define LDP 68
__global__ __launch_bounds__(256) void lattn_kernel(
    const float* __restrict__ Lc, ushort* __restrict__ Out,
    const int* __restrict__ ip, const float* __restrict__ fpp) {
  __shared__ __align__(16) float Qs[HD_][LDP];
  __shared__ __align__(16) float KPs[64][LDP];
  __shared__ __align__(16) float Vs[64][LDP];
  const int n_win = ip[3];
  const int win = ip[0], span_len = ip[1], local_max = ip[2];
  const float sm = fpp[0], temp = fpp[1];
  const int bh = blockIdx.y;
  const int b = bh >> 4, h = bh & 15;
  const int tid = threadIdx.x;
  const int tx = tid & 15, ty = tid >> 4;
  const float sc = 0.35355339059327373f / temp;
  for (int w = blockIdx.x; w < n_win; w += gridDim.x) {
    const int st = w * win;
    const int en = min(st + win, S_); const int wlen = en - st;
    const int ks = max(0, st - span_len + win);
    const int ke = min(st + span_len, S_); const int klen = ke - ks;
    int eff = (int)((double)wlen * (double)sm);
    eff = min(min(eff, wlen), min(klen, local_max));
    if (eff > 0) {
      const int nt = (eff + 63) >> 6;
      for (int qt = 0; qt < nt; ++qt) {
        const int qn = min(64, eff - qt*64);
        __syncthreads();
        #pragma unroll
        for (int c = 0; c < 4; c++) {
          int f = tid + c*256;
          int r = f >> 4;
          int dc = (f & 15) << 2;
          float4 q4 = make_float4(0.f,0.f,0.f,0.f);
          if (r < qn) q4 = *(const float4*)(Lc + ((size_t)(b*S_ + st + qt*64 + r)) * D_ + h*HD_ + dc);
          Qs[dc+0][r]=q4.x; Qs[dc+1][r]=q4.y; Qs[dc+2][r]=q4.z; Qs[dc+3][r]=q4.w;
        }
        float o[4][4] = {{0.f,0.f,0.f,0.f},{0.f,0.f,0.f,0.f},{0.f,0.f,0.f,0.f},{0.f,0.f,0.f,0.f}};
        float mrow[4], lrow[4];
        #pragma unroll
        for (int i=0;i<4;i++){ mrow[i] = -INFINITY; lrow[i] = 0.f; }
        for (int kt = 0; kt < nt; ++kt) {
          const int kn = min(64, eff - kt*64);
          __syncthreads();
          #pragma unroll
          for (int c = 0; c < 4; c++) {
            int f = tid + c*256;
            int r = f >> 4;
            int dc = (f & 15) << 2;
            float4 k4 = make_float4(0.f,0.f,0.f,0.f);
            if (r < kn) k4 = *(const float4*)(Lc + ((size_t)(b*S_ + ks + kt*64 + r)) * D_ + h*HD_ + dc);
            KPs[dc+0][r]=k4.x; KPs[dc+1][r]=k4.y; KPs[dc+2][r]=k4.z; KPs[dc+3][r]=k4.w;
            *(float4*)&Vs[r][dc] = k4;
          }
          __syncthreads();
          float s[4][4] = {{0.f,0.f,0.f,0.f},{0.f,0.f,0.f,0.f},{0.f,0.f,0.f,0.f},{0.f,0.f,0.f,0.f}};
          #pragma unroll 8
          for (int d = 0; d < HD_; ++d) {
            const float4 a  = *(const float4*)&Qs[d][ty*4];
            const float4 bb = *(const float4*)&KPs[d][tx*4];
            const float av[4]={a.x,a.y,a.z,a.w};
            const float bv[4]={bb.x,bb.y,bb.z,bb.w};
            #pragma unroll
            for (int i=0;i<4;i++)
              #pragma unroll
              for (int j=0;j<4;j++)
                s[i][j] += av[i]*bv[j];
          }
          #pragma unroll
          for (int i=0;i<4;i++) {
            #pragma unroll
            for (int j=0;j<4;j++) {
              float lg = s[i][j]*sc;
              if (kt*64 + tx*4 + j >= eff) lg = -INFINITY;
              s[i][j] = lg;
            }
          }
          #pragma unroll
          for (int i=0;i<4;i++) {
            float tm = fmaxf(fmaxf(s[i][0],s[i][1]), fmaxf(s[i][2],s[i][3]));
            #pragma unroll
            for (int off=1; off<16; off<<=1) tm = fmaxf(tm, __shfl_xor(tm, off, 64));
            const float nm = fmaxf(mrow[i], tm);
            const float alpha = __expf(mrow[i]-nm);
            float ps = 0.f;
            #pragma unroll
            for (int j=0;j<4;j++){ float p = __expf(s[i][j]-nm); s[i][j]=p; ps += p; }
            #pragma unroll
            for (int off=1; off<16; off<<=1) ps += __shfl_xor(ps, off, 64);
            lrow[i] = lrow[i]*alpha + ps;
            mrow[i] = nm;
            #pragma unroll
            for (int j=0;j<4;j++) o[i][j] *= alpha;
          }
          __syncthreads();
          #pragma unroll
          for (int i=0;i<4;i++)
            #pragma unroll
            for (int j=0;j<4;j++)
              KPs[tx*4+j][ty*4+i] = s[i][j];
          __syncthreads();
          #pragma unroll 8
          for (int kk = 0; kk < 64; ++kk) {
            const float4 a  = *(const float4*)&KPs[kk][ty*4];
            const float4 bb = *(const float4*)&Vs[kk][tx*4];
            const float av[4]={a.x,a.y,a.z,a.w};
            const float bv[4]={bb.x,bb.y,bb.z,bb.w};
            #pragma unroll
            for (int i=0;i<4;i++)
              #pragma unroll
              for (int j=0;j<4;j++)
                o[i][j] += av[i]*bv[j];
          }
        }
        #pragma unroll
        for (int i=0;i<4;i++){
          const int r = ty*4 + i;
          if (r < qn) {
            const float inv = 1.0f / lrow[i];
            ushort4 ov;
            ov.x = f2bf(o[i][0]*inv); ov.y = f2bf(o[i][1]*inv);
            ov.z = f2bf(o[i][2]*inv); ov.w = f2bf(o[i][3]*inv);
            *(ushort4*)(Out + ((size_t)(b*S_ + st + qt*64 + r)) * 2048 + h*HD_ + tx*4) = ov;
          }
        }
      }
    }
    const ushort4 z = {0,0,0,0};
    for (int r = max(eff, 0) + ty; r < wlen; r += 16)
      *(ushort4*)(Out + ((size_t)(b*S_ + st + r)) * 2048 + h*HD_ + tx*4) = z;
  }
}

// ---------------- launch ----------------
extern "C" void kernel_launch(void* const* d_in, const int* in_sizes, int n_in,
                              void* d_out, int out_size, void* d_ws, size_t ws_size,
                              hipStream_t stream) {
  const float* x      = (const float*)d_in[0];
  const float* ln_a_g = (const float*)d_in[1];
  const float* ln_a_b = (const float*)d_in[2];
  const float* ln_b_g = (const float*)d_in[3];
  const float* ln_b_b = (const float*)d_in[4];
  const float* Wq     = (const float*)d_in[5];
  const float* bq     = (const float*)d_in[6];
  const float* Wk     = (const float*)d_in[7];
  const float* Wv     = (const float*)d_in[8];
  const float* bv     = (const float*)d_in[9];
  const float* Wo     = (const float*)d_in[10];
  const float* bo     = (const float*)d_in[11];
  const float* Wp     = (const float*)d_in[12];
  const float* bp     = (const float*)d_in[13];
  const float* Wproj  = (const float*)d_in[14];
  const float* bproj  = (const float*)d_in[15];
  float* out = (float*)d_out;
  float* ws  = (float*)d_ws;
  ushort* wsu = (ushort*)d_ws;

  // ws layout:
  ushort* Qsp = wsu;                         // [64*1024,128] 16.8MB
  ushort* Ksp = wsu + 8388608;               // [64*1024,128] 16.8MB
  ushort* Vth = wsu + 16777216;              // [64*64,1024]  8.4MB
  ushort* Vtl = wsu + 20971520;              // [64*64,1024]  8.4MB
  ushort* B3  = (ushort*)(ws + 12582912);    // [1024,2048] bf16
  float* glo  = ws + 16777216;               // [4096,1024] globe_out
  float* loc  = ws + 20971520;               // [4096,1024] LN_a out
  float* biascat = ws + 25165824;            // [3072]
  float* mbd  = biascat + 4096;
  float* fpar = mbd + 4096;
  int*   ipar = (int*)(fpar + 8);
  ushort* Acat  = (ushort*)(ws + 25182208);  // [4096,2048] bf16
  ushort* Bqkv  = Acat + 12582912;           // [3072,2048] bf16
  ushort* Bo    = Bqkv + 9437184;            // [1024,2048] bf16
  float*  part = (float*)Acat;               // reuse after Acat dead
  ushort* A3  = wsu;                         // [4096,2048] overlays Qsp (dead)

  const dim3 blk(256);

  // one-time: allow 64KB dynamic LDS for the pipelined QKV kernel
  static int qkv_path = -1;
  if (qkv_path < 0) {
    hipError_t e = hipFuncSetAttribute(
        reinterpret_cast<const void*>(qkv4_kernel),
        hipFuncAttributeMaxDynamicSharedMemorySize, 65536);
    qkv_path = (e == hipSuccess) ? 1 : 0;
  }

  // 1) all input prep in one dispatch
  prep_kernel<<<dim3(14336), blk, 0, stream>>>(
      x, ln_a_g, ln_a_b, ln_b_g, ln_b_b, Wq, Wk, Wv, bq, bv, Wo, Wproj,
      Acat, Bqkv, biascat, loc, B3, Bo);
  // 2) QKV GEMM with fused split epilogue -> Qsp/Ksp/Vth/Vtl
  if (qkv_path)
    qkv4_kernel<<<dim3(24, 32), blk, 65536, stream>>>(
        Acat, Bqkv, biascat, Qsp, Ksp, Vth, Vtl);
  else
    mfma_gemm_qkv<<<dim3(24, 32), blk, 0, stream>>>(Acat, Bqkv, biascat,
                                                    Qsp, Ksp, Vth, Vtl, 1024);
  // 3) MFMA causal attention (epoch-balanced pairing + T5 setprio) -> Acat
  gattn_mfma<<<dim3(8, 64), blk, 0, stream>>>(Qsp, Ksp, Vth, Vtl, Acat);
  // 4) globe_out = attn · Wo^T + bo
  mfma_gemm2<<<dim3(8, 64), blk, 0, stream>>>(Acat, Bo, bo, glo, 1024, 1024, A3);
  // 5) predictor (device-side)
  seqmean1_kernel<<<dim3(4, 8, B_), blk, 0, stream>>>(glo, part);
  seqmean2_kernel<<<dim3(4, B_), blk, 0, stream>>>(part, mbd);
  predictor_kernel<<<dim3(1), blk, 0, stream>>>(mbd, Wp, bp, fpar, ipar);
  // 6) local attention -> A3[:, 0:1024] bf16 (self-zeroing)
  lattn_kernel<<<dim3(64, B_*H_), blk, 0, stream>>>(loc, A3, ipar, fpar);
  // 7) out = A3 · B3^T + bproj
  mfma_gemm<<<dim3(8, 64), blk, 0, stream>>>(A3, B3, bproj, out, 2048, 1024);
}

// Round 10
// 412.890 us; speedup vs baseline: 1.0276x; 1.0276x over previous
//
#include <hip/hip_runtime.h>
#include <math.h>

#define B_ 4
#define S_ 1024
#define D_ 1024
#define H_ 16
#define HD_ 64
#define BSD_ (B_*S_*D_)

using short8 = __attribute__((ext_vector_type(8))) short;
using f32x4  = __attribute__((ext_vector_type(4))) float;

#define MFMA16(a,b,c) __builtin_amdgcn_mfma_f32_16x16x32_bf16((a),(b),(c),0,0,0)

// ---------------- bf16 helpers (RNE) ----------------
__device__ __forceinline__ ushort f2bf(float f) {
  uint u = __float_as_uint(f);
  return (ushort)((u + 0x7fffu + ((u >> 16) & 1u)) >> 16);
}
__device__ __forceinline__ float bf2f(ushort h) {
  return __uint_as_float(((uint)h) << 16);
}
__device__ __forceinline__ void split8(const float* p, short8* hi, short8* lo) {
  #pragma unroll
  for (int j = 0; j < 8; j++) {
    ushort h = f2bf(p[j]);
    (*hi)[j] = (short)h;
    (*lo)[j] = (short)f2bf(p[j] - bf2f(h));
  }
}
// async global->LDS, 16B per lane; LDS dest = wave-uniform base + lane*16
__device__ __forceinline__ void async_load16(const ushort* g, ushort* l) {
  __builtin_amdgcn_global_load_lds(
      (const __attribute__((address_space(1))) unsigned int*)g,
      (__attribute__((address_space(3))) unsigned int*)l, 16, 0, 0);
}

// ---------------- block reduce (256 threads = 4 waves) ----------------
__device__ __forceinline__ float block_reduce_sum_256(float v, float* sbuf) {
  #pragma unroll
  for (int off = 32; off > 0; off >>= 1) v += __shfl_xor(v, off, 64);
  int lane = threadIdx.x & 63, wid = threadIdx.x >> 6;
  __syncthreads();
  if (lane == 0) sbuf[wid] = v;
  __syncthreads();
  return sbuf[0] + sbuf[1] + sbuf[2] + sbuf[3];
}

__device__ __forceinline__ void split4_store(const float4 a, ushort* orow, int c, int stride) {
  ushort4 hi, lo;
  hi.x = f2bf(a.x); hi.y = f2bf(a.y); hi.z = f2bf(a.z); hi.w = f2bf(a.w);
  lo.x = f2bf(a.x - bf2f(hi.x)); lo.y = f2bf(a.y - bf2f(hi.y));
  lo.z = f2bf(a.z - bf2f(hi.z)); lo.w = f2bf(a.w - bf2f(hi.w));
  *(ushort4*)(orow + c)          = hi;
  *(ushort4*)(orow + stride + c) = lo;
}

// ---------------- fused prep: all input-side transforms in ONE dispatch ----------
__global__ __launch_bounds__(256) void prep_kernel(
    const float* __restrict__ x,
    const float* __restrict__ ln_a_g, const float* __restrict__ ln_a_b,
    const float* __restrict__ ln_b_g, const float* __restrict__ ln_b_b,
    const float* __restrict__ Wq, const float* __restrict__ Wk,
    const float* __restrict__ Wv, const float* __restrict__ bq,
    const float* __restrict__ bv, const float* __restrict__ Wo,
    const float* __restrict__ Wproj,
    ushort* __restrict__ Acat, ushort* __restrict__ Bqkv,
    float* __restrict__ biascat, float* __restrict__ loc,
    ushort* __restrict__ B3, ushort* __restrict__ Bo) {
  __shared__ float sbuf[4];
  const int bx = blockIdx.x;
  const int t = threadIdx.x;
  if (bx < 4096) {
    const int row = bx;
    const int c = t*4;
    const float* xr = x + (size_t)row * D_;
    float4 v = *(const float4*)(xr + c);
    float s = v.x + v.y + v.z + v.w;
    const float mean = block_reduce_sum_256(s, sbuf) * (1.0f/D_);
    float4 dv = make_float4(v.x-mean, v.y-mean, v.z-mean, v.w-mean);
    float sq = dv.x*dv.x + dv.y*dv.y + dv.z*dv.z + dv.w*dv.w;
    const float var = block_reduce_sum_256(sq, sbuf) * (1.0f/D_);
    const float r = rsqrtf(var + 1e-5f);
    float4 gg = *(const float4*)(ln_b_g + c);
    float4 bb = *(const float4*)(ln_b_b + c);
    float4 n;
    n.x = dv.x*r*gg.x + bb.x; n.y = dv.y*r*gg.y + bb.y;
    n.z = dv.z*r*gg.z + bb.z; n.w = dv.w*r*gg.w + bb.w;
    split4_store(n, Acat + (size_t)row*2048, c, 1024);
  } else if (bx < 7168) {
    const int idx = (bx - 4096)*256 + t;
    const int n = idx >> 8;
    const int col4 = (idx & 255) << 2;
    const float* src = (n < 1024) ? (Wq + (size_t)n*1024)
                     : (n < 2048) ? (Wk + (size_t)(n-1024)*1024)
                                  : (Wv + (size_t)(n-2048)*1024);
    const float4 a = *(const float4*)(src + col4);
    split4_store(a, Bqkv + (size_t)n*2048, col4, 1024);
    if (idx < 3072)
      biascat[idx] = (idx < 1024) ? bq[idx] : (idx < 2048) ? 0.f : bv[idx-2048];
  } else if (bx < 11264) {
    const int row = bx - 7168;
    const float* xr = x + (size_t)row * D_;
    float v[4]; float s = 0.f;
    #pragma unroll
    for (int i = 0; i < 4; i++) { v[i] = xr[t + 256*i]; s += v[i]; }
    const float mean = block_reduce_sum_256(s, sbuf) * (1.0f/D_);
    float sq = 0.f;
    #pragma unroll
    for (int i = 0; i < 4; i++) { float d = v[i]-mean; sq += d*d; }
    const float var = block_reduce_sum_256(sq, sbuf) * (1.0f/D_);
    const float r = rsqrtf(var + 1e-5f);
    float* orow = loc + (size_t)row * D_;
    #pragma unroll
    for (int i = 0; i < 4; i++) {
      int c = t + 256*i;
      orow[c] = (v[i]-mean)*r*ln_a_g[c] + ln_a_b[c];
    }
  } else if (bx < 13312) {
    const int idx = (bx - 11264)*256 + t;
    const int row = idx >> 9;
    const int col4 = (idx & 511) << 2;
    const float4 a = *(const float4*)(Wproj + (size_t)row*2048 + col4);
    ushort4 hi;
    hi.x = f2bf(a.x); hi.y = f2bf(a.y); hi.z = f2bf(a.z); hi.w = f2bf(a.w);
    *(ushort4*)(B3 + (size_t)row*2048 + col4) = hi;
  } else {
    const int idx = (bx - 13312)*256 + t;
    const int n = idx >> 8;
    const int col4 = (idx & 255) << 2;
    const float4 a = *(const float4*)(Wo + (size_t)n*1024 + col4);
    split4_store(a, Bo + (size_t)n*2048, col4, 1024);
  }
}

// =====================================================================
// 128x128 pipelined QKV GEMM (R9 win): single-sync K-groups.
// =====================================================================
#define BARRIER() asm volatile("s_barrier" ::: "memory")
#define VMW(n)  asm volatile("s_waitcnt vmcnt(" #n ")" ::: "memory")

#define STAGE4(k0, SBs) do { \
  _Pragma("unroll") \
  for (int i_ = 0; i_ < 2; ++i_) { \
    const int cid_ = wave*2 + i_, hl_ = cid_>>2, rs_ = cid_&3; \
    const int r0_ = (rs_>>1)*64 + (rs_&1)*16; \
    async_load16(A  + ((size_t)(bm + r0_ + lrow) << 11) + (hl_ << 10) + (k0) + sw, \
                 (SBs) + hl_*4096 + r0_*32); \
  } \
  _Pragma("unroll") \
  for (int i_ = 0; i_ < 2; ++i_) { \
    const int cid_ = wave*2 + i_, hl_ = cid_>>2, rs_ = cid_&3; \
    const int r0_ = (rs_>>1)*64 + (rs_&1)*16; \
    async_load16(Bw + ((size_t)(bn + r0_ + lrow) << 11) + (hl_ << 10) + (k0) + sw, \
                 (SBs) + 8192 + hl_*4096 + r0_*32); \
  } \
  _Pragma("unroll") \
  for (int i_ = 0; i_ < 2; ++i_) { \
    const int cid_ = wave*2 + i_, hl_ = cid_>>2, rs_ = cid_&3; \
    const int r1_ = (rs_>>1)*64 + (rs_&1)*16 + 32; \
    async_load16(Bw + ((size_t)(bn + r1_ + lrow) << 11) + (hl_ << 10) + (k0) + sw, \
                 (SBs) + 8192 + hl_*4096 + r1_*32); \
  } \
  _Pragma("unroll") \
  for (int i_ = 0; i_ < 2; ++i_) { \
    const int cid_ = wave*2 + i_, hl_ = cid_>>2, rs_ = cid_&3; \
    const int r1_ = (rs_>>1)*64 + (rs_&1)*16 + 32; \
    async_load16(A  + ((size_t)(bm + r1_ + lrow) << 11) + (hl_ << 10) + (k0) + sw, \
                 (SBs) + hl_*4096 + r1_*32); \
  } \
} while (0)

#define PH4(mh, nh, SBc, STG) do { \
  short8 ah_[2], al_[2], bh_[2], bl_[2]; \
  _Pragma("unroll") \
  for (int m4_ = 0; m4_ < 2; ++m4_) { \
    const int ro_ = (wm*64 + (mh)*32 + m4_*16 + lm)*32 + rsw; \
    ah_[m4_] = *(const short8*)&(SBc)[ro_]; \
    al_[m4_] = *(const short8*)&(SBc)[4096 + ro_]; } \
  _Pragma("unroll") \
  for (int n2_ = 0; n2_ < 2; ++n2_) { \
    const int ro_ = (wn*64 + (nh)*32 + n2_*16 + lm)*32 + rsw; \
    bh_[n2_] = *(const short8*)&(SBc)[8192 + ro_]; \
    bl_[n2_] = *(const short8*)&(SBc)[12288 + ro_]; } \
  STG; \
  __builtin_amdgcn_s_setprio(1); \
  _Pragma("unroll") \
  for (int m4_ = 0; m4_ < 2; ++m4_) \
    _Pragma("unroll") \
    for (int n2_ = 0; n2_ < 2; ++n2_) { \
      f32x4 t_ = acc[(mh)*2+m4_][(nh)*2+n2_]; \
      t_ = MFMA16(ah_[m4_], bh_[n2_], t_); \
      t_ = MFMA16(al_[m4_], bh_[n2_], t_); \
      t_ = MFMA16(ah_[m4_], bl_[n2_], t_); \
      acc[(mh)*2+m4_][(nh)*2+n2_] = t_; } \
  __builtin_amdgcn_s_setprio(0); \
} while (0)

#define GROUP4(g, SBc, SBs) do { \
  const int k0n_ = (((g) + 1) & 31) * 32; \
  PH4(0, 0, (SBc), STAGE4(k0n_, (SBs))); \
  PH4(0, 1, (SBc), ((void)0)); \
  PH4(1, 0, (SBc), ((void)0)); \
  PH4(1, 1, (SBc), ((void)0)); \
  VMW(0); \
  BARRIER(); \
} while (0)

__global__ __launch_bounds__(256, 2) void qkv4_kernel(
    const ushort* __restrict__ A, const ushort* __restrict__ Bw,
    const float* __restrict__ bias,
    ushort* __restrict__ Qsp, ushort* __restrict__ Ksp,
    ushort* __restrict__ Vth, ushort* __restrict__ Vtl) {
  extern __shared__ __align__(16) ushort smem[];   // 2 slots x 32KB
  const int tid = threadIdx.x;
  const int bm = blockIdx.y * 128, bn = blockIdx.x * 128;
  const int wave = tid >> 6, lane = tid & 63;
  const int wm = wave >> 1, wn = wave & 1;
  const int lm = lane & 15, q = lane >> 4;
  const int lrow = lane >> 2;
  const int sw = (((lane & 3) ^ ((lane >> 3) & 3)) << 3);
  const int rsw = ((q ^ ((lm >> 1) & 3)) << 3);

  f32x4 acc[4][4];
  #pragma unroll
  for (int i = 0; i < 4; i++)
    #pragma unroll
    for (int j = 0; j < 4; j++)
      acc[i][j] = (f32x4){0.f,0.f,0.f,0.f};

  STAGE4(0, smem);
  VMW(0); BARRIER();

  #pragma unroll 1
  for (int g = 0; g < 32; g += 2) {
    GROUP4(g,     smem,         smem + 16384);
    GROUP4(g + 1, smem + 16384, smem);
  }
  VMW(0);
  __syncthreads();

  const int b = bm >> 10, s0 = bm & 1023;
  if (blockIdx.x < 16) {
    ushort* dst = (blockIdx.x < 8) ? Qsp : Ksp;
    #pragma unroll
    for (int mt = 0; mt < 4; mt++) {
      #pragma unroll
      for (int nt = 0; nt < 4; nt++) {
        const int n = bn + wn*64 + nt*16 + lm;
        const int h = (n >> 6) & 15;
        const int d = nt*16 + lm;
        const float bb = bias[n];
        #pragma unroll
        for (int reg = 0; reg < 4; reg++) {
          const int s = s0 + wm*64 + mt*16 + q*4 + reg;
          const float val = acc[mt][nt][reg] + bb;
          const ushort hi = f2bf(val);
          const ushort lo = f2bf(val - bf2f(hi));
          ushort* rp = dst + ((size_t)((b*16 + h)*1024 + s))*128;
          rp[d] = hi; rp[64 + d] = lo;
        }
      }
    }
  } else {
    ushort* Th = smem;            // [64][136] ushorts
    ushort* Tl = smem + 8704;
    #pragma unroll
    for (int c = 0; c < 2; c++) {
      __syncthreads();
      if (wn == c) {
        #pragma unroll
        for (int mt = 0; mt < 4; mt++)
          #pragma unroll
          for (int nt = 0; nt < 4; nt++) {
            const int nl = nt*16 + lm;
            const float bb = bias[bn + c*64 + nl];
            #pragma unroll
            for (int reg = 0; reg < 4; reg++) {
              const int sl = wm*64 + mt*16 + q*4 + reg;
              const float val = acc[mt][nt][reg] + bb;
              const ushort hi = f2bf(val);
              const ushort lo = f2bf(val - bf2f(hi));
              Th[nl*136 + sl] = hi;
              Tl[nl*136 + sl] = lo;
            }
          }
      }
      __syncthreads();
      const int nl = tid >> 2, s32 = (tid & 3)*32;
      const int h = ((bn - 2048 + c*64) >> 6) & 15;
      const size_t drow = ((size_t)((b*16 + h)*64 + nl))*1024 + s0 + s32;
      #pragma unroll
      for (int j = 0; j < 4; j++) {
        *(short8*)(Vth + drow + j*8) = *(const short8*)&Th[nl*136 + s32 + j*8];
        *(short8*)(Vtl + drow + j*8) = *(const short8*)&Tl[nl*136 + s32 + j*8];
      }
    }
  }
}

// ------- dual-panel bf16x3 MFMA GEMM, 64x128 tile, R10 single-sync dbuf ----------
// Per slot layout (ushorts): Ash@0 (2048) | Asl@2048 | Bsh@4096 (4096) | Bsl@8192
#define G2_STAGE(k0, slot) do { \
  _Pragma("unroll") \
  for (int i_ = 0; i_ < 6; ++i_) \
    async_load16(gsrc[i_] + (k0), &S2[slot][loff[i_]]); \
} while (0)

#define G2_STEP(slot) do { \
  const ushort* P_ = &S2[slot][0]; \
  short8 ah_[4], al_[4], bh_[2], bl_[2]; \
  _Pragma("unroll") \
  for (int mt_ = 0; mt_ < 4; mt_++) { \
    ah_[mt_] = *(const short8*)&P_[aoff + mt_*512]; \
    al_[mt_] = *(const short8*)&P_[2048 + aoff + mt_*512]; } \
  _Pragma("unroll") \
  for (int nt_ = 0; nt_ < 2; nt_++) { \
    bh_[nt_] = *(const short8*)&P_[4096 + boff + nt_*512]; \
    bl_[nt_] = *(const short8*)&P_[8192 + boff + nt_*512]; } \
  __builtin_amdgcn_s_setprio(1); \
  _Pragma("unroll") \
  for (int mt_ = 0; mt_ < 4; mt_++) \
    _Pragma("unroll") \
    for (int nt_ = 0; nt_ < 2; nt_++) { \
      f32x4 a_ = acc[mt_][nt_]; \
      a_ = MFMA16(ah_[mt_], bh_[nt_], a_); \
      a_ = MFMA16(al_[mt_], bh_[nt_], a_); \
      a_ = MFMA16(ah_[mt_], bl_[nt_], a_); \
      acc[mt_][nt_] = a_; } \
  __builtin_amdgcn_s_setprio(0); \
} while (0)

__global__ __launch_bounds__(256) void mfma_gemm2(
    const ushort* __restrict__ A, const ushort* __restrict__ Bw,
    const float* __restrict__ bias, float* __restrict__ C,
    int Kh, int ldc, ushort* __restrict__ aux) {
  __shared__ __align__(16) ushort S2[2][12288];   // 48KB total
  const int lda = 2*Kh;
  const int tid = threadIdx.x;
  const int bm = blockIdx.y * 64, bn = blockIdx.x * 128;
  const int wave = tid >> 6, lane = tid & 63;
  const int lm = lane & 15, q = lane >> 4;
  const int lrow = lane >> 2;
  const int sw = (((lane & 3) ^ ((lane >> 3) & 3)) << 3);

  f32x4 acc[4][2];
  #pragma unroll
  for (int i = 0; i < 4; i++)
    #pragma unroll
    for (int j = 0; j < 2; j++)
      acc[i][j] = (f32x4){0.f,0.f,0.f,0.f};

  const ushort* gsrc[6];
  int loff[6];
  #pragma unroll
  for (int i = 0; i < 6; i++) {
    const int s = wave*6 + i;
    const ushort* gp; int lp;
    if (s < 4)       { gp = A  + (size_t)(bm + s*16 + lrow)*lda + sw;           lp = (s*16)*32; }
    else if (s < 8)  { gp = A  + (size_t)(bm + (s-4)*16 + lrow)*lda + Kh + sw;  lp = 2048 + ((s-4)*16)*32; }
    else if (s < 16) { gp = Bw + (size_t)(bn + (s-8)*16 + lrow)*lda + sw;       lp = 4096 + ((s-8)*16)*32; }
    else             { gp = Bw + (size_t)(bn + (s-16)*16 + lrow)*lda + Kh + sw; lp = 8192 + ((s-16)*16)*32; }
    gsrc[i] = gp; loff[i] = lp;
  }
  const int rsw = ((q ^ ((lm >> 1) & 3)) << 3);
  const int aoff = lm*32 + rsw;
  const int boff = (wave*32 + lm)*32 + rsw;

  G2_STAGE(0, 0);
  VMW(0); BARRIER();

  #pragma unroll 1
  for (int k0 = 0; k0 < Kh; k0 += 64) {
    if (k0 + 32 < Kh) G2_STAGE(k0 + 32, 1);
    G2_STEP(0);
    VMW(0); BARRIER();
    if (k0 + 64 < Kh) G2_STAGE(k0 + 64, 0);
    G2_STEP(1);
    VMW(0); BARRIER();
  }

  #pragma unroll
  for (int mt = 0; mt < 4; mt++) {
    #pragma unroll
    for (int nt = 0; nt < 2; nt++) {
      const int n = bn + wave*32 + nt*16 + lm;
      const float bb = bias ? bias[n] : 0.f;
      #pragma unroll
      for (int reg = 0; reg < 4; reg++) {
        const int m = bm + mt*16 + q*4 + reg;
        const float val = acc[mt][nt][reg] + bb;
        C[(size_t)m*ldc + n] = val;
        if (aux) aux[(size_t)m*2048 + 1024 + n] = f2bf(val);
      }
    }
  }
}

// ---------- plain bf16 MFMA GEMM, 64x128 tile, R10 single-sync dbuf --------------
// Per slot layout (ushorts): As@0 (2048) | Bs@2048 (4096)
#define G1_STAGE(k0, slot) do { \
  _Pragma("unroll") \
  for (int i_ = 0; i_ < 3; ++i_) \
    async_load16(gsrc[i_] + (k0), &S1[slot][loff[i_]]); \
} while (0)

#define G1_STEP(slot) do { \
  const ushort* P_ = &S1[slot][0]; \
  short8 af_[4], bf_[2]; \
  _Pragma("unroll") \
  for (int mt_ = 0; mt_ < 4; mt_++) af_[mt_] = *(const short8*)&P_[aoff + mt_*512]; \
  _Pragma("unroll") \
  for (int nt_ = 0; nt_ < 2; nt_++) bf_[nt_] = *(const short8*)&P_[2048 + boff + nt_*512]; \
  __builtin_amdgcn_s_setprio(1); \
  _Pragma("unroll") \
  for (int mt_ = 0; mt_ < 4; mt_++) \
    _Pragma("unroll") \
    for (int nt_ = 0; nt_ < 2; nt_++) \
      acc[mt_][nt_] = MFMA16(af_[mt_], bf_[nt_], acc[mt_][nt_]); \
  __builtin_amdgcn_s_setprio(0); \
} while (0)

__global__ __launch_bounds__(256) void mfma_gemm(
    const ushort* __restrict__ A, const ushort* __restrict__ Bw,
    const float* __restrict__ bias, float* __restrict__ C,
    int K, int ldc) {
  __shared__ __align__(16) ushort S1[2][6144];    // 24KB total
  const int tid = threadIdx.x;
  const int bm = blockIdx.y * 64, bn = blockIdx.x * 128;
  const int wave = tid >> 6, lane = tid & 63;
  const int lm = lane & 15, q = lane >> 4;
  const int lrow = lane >> 2;
  const int sw = (((lane & 3) ^ ((lane >> 3) & 3)) << 3);

  f32x4 acc[4][2];
  #pragma unroll
  for (int i = 0; i < 4; i++)
    #pragma unroll
    for (int j = 0; j < 2; j++)
      acc[i][j] = (f32x4){0.f,0.f,0.f,0.f};

  const ushort* gsrc[3];
  int loff[3];
  #pragma unroll
  for (int i = 0; i < 3; i++) {
    const int s = wave*3 + i;
    const ushort* gp; int lp;
    if (s < 4) { gp = A  + (size_t)(bm + s*16 + lrow)*K + sw;     lp = (s*16)*32; }
    else       { gp = Bw + (size_t)(bn + (s-4)*16 + lrow)*K + sw; lp = 2048 + ((s-4)*16)*32; }
    gsrc[i] = gp; loff[i] = lp;
  }
  const int rsw = ((q ^ ((lm >> 1) & 3)) << 3);
  const int aoff = lm*32 + rsw;
  const int boff = (wave*32 + lm)*32 + rsw;

  G1_STAGE(0, 0);
  VMW(0); BARRIER();

  #pragma unroll 1
  for (int k0 = 0; k0 < K; k0 += 64) {
    if (k0 + 32 < K) G1_STAGE(k0 + 32, 1);
    G1_STEP(0);
    VMW(0); BARRIER();
    if (k0 + 64 < K) G1_STAGE(k0 + 64, 0);
    G1_STEP(1);
    VMW(0); BARRIER();
  }

  #pragma unroll
  for (int mt = 0; mt < 4; mt++) {
    #pragma unroll
    for (int nt = 0; nt < 2; nt++) {
      const int n = bn + wave*32 + nt*16 + lm;
      const float bb = bias ? bias[n] : 0.f;
      #pragma unroll
      for (int reg = 0; reg < 4; reg++) {
        const int m = bm + mt*16 + q*4 + reg;
        C[(size_t)m*ldc + n] = acc[mt][nt][reg] + bb;
      }
    }
  }
}

// ---- one q-tile x k-tile attention unit (scores -> softmax -> PV) ----
// T5: setprio(1) around both MFMA clusters (R8 win).
__device__ __forceinline__ void attn_unit(
    int qt, int kt, int w, int lm, int q,
    const short8 qh[2], const short8 ql[2],
    const ushort* Kc, const ushort* Vc, float* Pf,
    f32x4 of[4], float mst[4], float lst[4]) {
  f32x4 sS[4];
  __builtin_amdgcn_s_setprio(1);
  #pragma unroll
  for (int nt = 0; nt < 4; nt++) {
    const ushort* kr = &Kc[(nt*16 + lm)*136 + q*8];
    const short8 kh0 = *(const short8*)(kr);
    const short8 kh1 = *(const short8*)(kr + 32);
    const short8 kl0 = *(const short8*)(kr + 64);
    const short8 kl1 = *(const short8*)(kr + 96);
    f32x4 a = (f32x4){0.f,0.f,0.f,0.f};
    a = MFMA16(qh[0], kh0, a);
    a = MFMA16(ql[0], kh0, a);
    a = MFMA16(qh[0], kl0, a);
    a = MFMA16(qh[1], kh1, a);
    a = MFMA16(ql[1], kh1, a);
    a = MFMA16(qh[1], kl1, a);
    sS[nt] = a;
  }
  __builtin_amdgcn_s_setprio(0);
  const int ktbase = kt*64;
  const int qrow0 = qt*64 + w*16 + q*4;
  #pragma unroll
  for (int rm = 0; rm < 4; rm++) {
    const int qrow = qrow0 + rm;
    float v[4];
    #pragma unroll
    for (int nt = 0; nt < 4; nt++) {
      const int kcol = ktbase + nt*16 + lm;
      const float x = sS[nt][rm]*0.125f;
      v[nt] = (kcol <= qrow) ? x : -INFINITY;
    }
    float tm = fmaxf(fmaxf(v[0],v[1]), fmaxf(v[2],v[3]));
    #pragma unroll
    for (int off = 1; off < 16; off <<= 1) tm = fmaxf(tm, __shfl_xor(tm, off, 64));
    const float nm = fmaxf(mst[rm], tm);
    const float alpha = __expf(mst[rm] - nm);
    float ps = 0.f;
    #pragma unroll
    for (int nt = 0; nt < 4; nt++) {
      float p = __expf(v[nt] - nm);
      sS[nt][rm] = p;
      ps += p;
    }
    #pragma unroll
    for (int off = 1; off < 16; off <<= 1) ps += __shfl_xor(ps, off, 64);
    lst[rm] = lst[rm]*alpha + ps;
    mst[rm] = nm;
    #pragma unroll
    for (int nt = 0; nt < 4; nt++) of[nt][rm] *= alpha;
  }
  #pragma unroll
  for (int rm = 0; rm < 4; rm++)
    #pragma unroll
    for (int nt = 0; nt < 4; nt++)
      Pf[(w*16 + q*4 + rm)*66 + nt*16 + lm] = sS[nt][rm];
  short8 ph[2], pl[2];
  {
    const float* prow = &Pf[(w*16 + lm)*66];
    float pv[16];
    *(float4*)&pv[0]  = *(const float4*)(prow + q*8);
    *(float4*)&pv[4]  = *(const float4*)(prow + q*8 + 4);
    *(float4*)&pv[8]  = *(const float4*)(prow + 32 + q*8);
    *(float4*)&pv[12] = *(const float4*)(prow + 32 + q*8 + 4);
    split8(&pv[0], &ph[0], &pl[0]);
    split8(&pv[8], &ph[1], &pl[1]);
  }
  __builtin_amdgcn_s_setprio(1);
  #pragma unroll
  for (int nt = 0; nt < 4; nt++) {
    const ushort* vr = &Vc[(nt*16 + lm)*136 + q*8];
    const short8 vh0 = *(const short8*)(vr);
    const short8 vh1 = *(const short8*)(vr + 32);
    const short8 vl0 = *(const short8*)(vr + 64);
    const short8 vl1 = *(const short8*)(vr + 96);
    f32x4 a = of[nt];
    a = MFMA16(ph[0], vh0, a);
    a = MFMA16(pl[0], vh0, a);
    a = MFMA16(ph[0], vl0, a);
    a = MFMA16(ph[1], vh1, a);
    a = MFMA16(pl[1], vh1, a);
    a = MFMA16(ph[1], vl1, a);
    of[nt] = a;
  }
  __builtin_amdgcn_s_setprio(0);
}

// ---- MFMA causal flash attention: dual q-tile, shared K/V staging ----
// XCD-aware epoch balancing (R7 win): per-CU epoch sum = 25, constant.
__global__ __launch_bounds__(256) void gattn_mfma(
    const ushort* __restrict__ Qsp, const ushort* __restrict__ Ksp,
    const ushort* __restrict__ Vth, const ushort* __restrict__ Vtl,
    ushort* __restrict__ Aout) {
  __shared__ __align__(16) ushort Kc[64*136];
  __shared__ __align__(16) ushort Vc[64*136];
  __shared__ __align__(16) float  Pf[64*66];
  const int bh = blockIdx.y;
  const int b = bh >> 4, h = bh & 15;
  const int tid = threadIdx.x;
  const int w = tid >> 6, lane = tid & 63;
  const int lm = lane & 15, q = lane >> 4;
  const ushort* Qb_ = Qsp + (size_t)bh * (1024*128);
  const ushort* Kb_ = Ksp + (size_t)bh * (1024*128);
  const ushort* Vhb = Vth + (size_t)bh * (64*1024);
  const ushort* Vlb = Vtl + (size_t)bh * (64*1024);
  const int half = (bh >> 5) & 1;
  const int qtA = half ? (8 + (int)blockIdx.x) : (15 - (int)blockIdx.x);
  const int qtB = half ? (7 - (int)blockIdx.x) : (int)blockIdx.x;

  short8 qhA[2], qlA[2], qhB[2], qlB[2];
  {
    const ushort* qr = Qb_ + (size_t)(qtA*64 + w*16 + lm)*128 + q*8;
    qhA[0] = *(const short8*)(qr);
    qhA[1] = *(const short8*)(qr + 32);
    qlA[0] = *(const short8*)(qr + 64);
    qlA[1] = *(const short8*)(qr + 96);
    const ushort* qr2 = Qb_ + (size_t)(qtB*64 + w*16 + lm)*128 + q*8;
    qhB[0] = *(const short8*)(qr2);
    qhB[1] = *(const short8*)(qr2 + 32);
    qlB[0] = *(const short8*)(qr2 + 64);
    qlB[1] = *(const short8*)(qr2 + 96);
  }
  f32x4 ofA[4], ofB[4];
  float mstA[4], lstA[4], mstB[4], lstB[4];
  #pragma unroll
  for (int nt = 0; nt < 4; nt++) {
    ofA[nt] = (f32x4){0.f,0.f,0.f,0.f};
    ofB[nt] = (f32x4){0.f,0.f,0.f,0.f};
  }
  #pragma unroll
  for (int rm = 0; rm < 4; rm++) {
    mstA[rm] = -INFINITY; lstA[rm] = 0.f;
    mstB[rm] = -INFINITY; lstB[rm] = 0.f;
  }

  for (int kt = 0; kt <= qtA; ++kt) {
    __syncthreads();
    #pragma unroll
    for (int i = 0; i < 4; i++) {
      const int slot = i*256 + tid;
      const int row = slot >> 4, c8 = slot & 15;
      *(float4*)&Kc[row*136 + c8*8] =
          *(const float4*)(Kb_ + (size_t)(kt*64 + row)*128 + c8*8);
      const ushort* vsrc = ((c8 < 8) ? Vhb : Vlb) + (size_t)row*1024 + kt*64 + (c8&7)*8;
      *(float4*)&Vc[row*136 + c8*8] = *(const float4*)vsrc;
    }
    __syncthreads();
    attn_unit(qtA, kt, w, lm, q, qhA, qlA, Kc, Vc, Pf, ofA, mstA, lstA);
    if (kt <= qtB)
      attn_unit(qtB, kt, w, lm, q, qhB, qlB, Kc, Vc, Pf, ofB, mstB, lstB);
  }

  #pragma unroll
  for (int rm = 0; rm < 4; rm++) {
    const float invA = 1.0f / lstA[rm];
    const int sA = qtA*64 + w*16 + q*4 + rm;
    ushort* arow = Aout + ((size_t)(b*1024 + sA))*2048 + h*64;
    #pragma unroll
    for (int nt = 0; nt < 4; nt++) {
      const float val = ofA[nt][rm] * invA;
      const ushort hi = f2bf(val);
      arow[nt*16 + lm] = hi;
      arow[1024 + nt*16 + lm] = f2bf(val - bf2f(hi));
    }
    const float invB = 1.0f / lstB[rm];
    const int sB = qtB*64 + w*16 + q*4 + rm;
    ushort* brow = Aout + ((size_t)(b*1024 + sB))*2048 + h*64;
    #pragma unroll
    for (int nt = 0; nt < 4; nt++) {
      const float val = ofB[nt][rm] * invB;
      const ushort hi = f2bf(val);
      brow[nt*16 + lm] = hi;
      brow[1024 + nt*16 + lm] = f2bf(val - bf2f(hi));
    }
  }
}

// ---------------- seq-mean, 2-stage deterministic ----------------
__global__ __launch_bounds__(256) void seqmean1_kernel(const float* __restrict__ g,
                                                       float* __restrict__ part) {
  const int d = blockIdx.x*256 + threadIdx.x;
  const int sc = blockIdx.y;
  const int b = blockIdx.z;
  const float* p = g + ((size_t)b*S_ + sc*128)*D_ + d;
  float s = 0.f;
  #pragma unroll 4
  for (int i = 0; i < 128; i++) s += p[(size_t)i*D_];
  part[((size_t)(b*8 + sc))*D_ + d] = s;
}
__global__ __launch_bounds__(256) void seqmean2_kernel(const float* __restrict__ part,
                                                       float* __restrict__ mbd) {
  const int d = blockIdx.x*256 + threadIdx.x;
  const int b = blockIdx.y;
  float s = 0.f;
  #pragma unroll
  for (int i = 0; i < 8; i++) s += part[((size_t)(b*8 + i))*D_ + d];
  mbd[b*D_ + d] = s * (1.0f/S_);
}

// ---------------- predictor ----------------
__global__ __launch_bounds__(256) void predictor_kernel(
    const float* __restrict__ mbd, const float* __restrict__ Wp,
    const float* __restrict__ bp, float* __restrict__ fpar, int* __restrict__ ipar) {
  __shared__ float sbuf[4];
  __shared__ float sdots[4];
  const int tid = threadIdx.x;
  for (int b = 0; b < 4; b++) {
    float psum = 0.f;
    for (int d = tid; d < D_; d += 256) psum += mbd[b*D_ + d]*Wp[d];
    float tot = block_reduce_sum_256(psum, sbuf);
    if (tid == 0) sdots[b] = tot;
  }
  __syncthreads();
  if (tid == 0) {
    float smv = 0.f;
    for (int b = 0; b < 4; b++) {
      float z = sdots[b] + bp[0];
      smv += 1.0f/(1.0f + expf(-z));
    }
    smv *= 0.25f;
    int win = max(1, (int)(256.0f*smv));
    int span_len = max(1, (int)(512.0f*smv));
    int local_max = min(512, min(span_len, win));
    float temp = 1.0f + 0.01f*(1.0f - smv);
    int n_win = (S_ + win - 1)/win;
    fpar[0] = smv; fpar[1] = temp;
    ipar[0] = win; ipar[1] = span_len; ipar[2] = local_max; ipar[3] = n_win;
  }
}

// -------- dynamic sliding-window span attention (fp32 -> bf16 out, self-zeroing) --
#define LDP 68
__global__ __launch_bounds__(256) void lattn_kernel(
    const float* __restrict__ Lc, ushort* __restrict__ Out,
    const int* __restrict__ ip, const float* __restrict__ fpp) {
  __shared__ __align__(16) float Qs[HD_][LDP];
  __shared__ __align__(16) float KPs[64][LDP];
  __shared__ __align__(16) float Vs[64][LDP];
  const int n_win = ip[3];
  const int win = ip[0], span_len = ip[1], local_max = ip[2];
  const float sm = fpp[0], temp = fpp[1];
  const int bh = blockIdx.y;
  const int b = bh >> 4, h = bh & 15;
  const int tid = threadIdx.x;
  const int tx = tid & 15, ty = tid >> 4;
  const float sc = 0.35355339059327373f / temp;
  for (int w = blockIdx.x; w < n_win; w += gridDim.x) {
    const int st = w * win;
    const int en = min(st + win, S_); const int wlen = en - st;
    const int ks = max(0, st - span_len + win);
    const int ke = min(st + span_len, S_); const int klen = ke - ks;
    int eff = (int)((double)wlen * (double)sm);
    eff = min(min(eff, wlen), min(klen, local_max));
    if (eff > 0) {
      const int nt = (eff + 63) >> 6;
      for (int qt = 0; qt < nt; ++qt) {
        const int qn = min(64, eff - qt*64);
        __syncthreads();
        #pragma unroll
        for (int c = 0; c < 4; c++) {
          int f = tid + c*256;
          int r = f >> 4;
          int dc = (f & 15) << 2;
          float4 q4 = make_float4(0.f,0.f,0.f,0.f);
          if (r < qn) q4 = *(const float4*)(Lc + ((size_t)(b*S_ + st + qt*64 + r)) * D_ + h*HD_ + dc);
          Qs[dc+0][r]=q4.x; Qs[dc+1][r]=q4.y; Qs[dc+2][r]=q4.z; Qs[dc+3][r]=q4.w;
        }
        float o[4][4] = {{0.f,0.f,0.f,0.f},{0.f,0.f,0.f,0.f},{0.f,0.f,0.f,0.f},{0.f,0.f,0.f,0.f}};
        float mrow[4], lrow[4];
        #pragma unroll
        for (int i=0;i<4;i++){ mrow[i] = -INFINITY; lrow[i] = 0.f; }
        for (int kt = 0; kt < nt; ++kt) {
          const int kn = min(64, eff - kt*64);
          __syncthreads();
          #pragma unroll
          for (int c = 0; c < 4; c++) {
            int f = tid + c*256;
            int r = f >> 4;
            int dc = (f & 15) << 2;
            float4 k4 = make_float4(0.f,0.f,0.f,0.f);
            if (r < kn) k4 = *(const float4*)(Lc + ((size_t)(b*S_ + ks + kt*64 + r)) * D_ + h*HD_ + dc);
            KPs[dc+0][r]=k4.x; KPs[dc+1][r]=k4.y; KPs[dc+2][r]=k4.z; KPs[dc+3][r]=k4.w;
            *(float4*)&Vs[r][dc] = k4;
          }
          __syncthreads();
          float s[4][4] = {{0.f,0.f,0.f,0.f},{0.f,0.f,0.f,0.f},{0.f,0.f,0.f,0.f},{0.f,0.f,0.f,0.f}};
          #pragma unroll 8
          for (int d = 0; d < HD_; ++d) {
            const float4 a  = *(const float4*)&Qs[d][ty*4];
            const float4 bb = *(const float4*)&KPs[d][tx*4];
            const float av[4]={a.x,a.y,a.z,a.w};
            const float bv[4]={bb.x,bb.y,bb.z,bb.w};
            #pragma unroll
            for (int i=0;i<4;i++)
              #pragma unroll
              for (int j=0;j<4;j++)
                s[i][j] += av[i]*bv[j];
          }
          #pragma unroll
          for (int i=0;i<4;i++) {
            #pragma unroll
            for (int j=0;j<4;j++) {
              float lg = s[i][j]*sc;
              if (kt*64 + tx*4 + j >= eff) lg = -INFINITY;
              s[i][j] = lg;
            }
          }
          #pragma unroll
          for (int i=0;i<4;i++) {
            float tm = fmaxf(fmaxf(s[i][0],s[i][1]), fmaxf(s[i][2],s[i][3]));
            #pragma unroll
            for (int off=1; off<16; off<<=1) tm = fmaxf(tm, __shfl_xor(tm, off, 64));
            const float nm = fmaxf(mrow[i], tm);
            const float alpha = __expf(mrow[i]-nm);
            float ps = 0.f;
            #pragma unroll
            for (int j=0;j<4;j++){ float p = __expf(s[i][j]-nm); s[i][j]=p; ps += p; }
            #pragma unroll
            for (int off=1; off<16; off<<=1) ps += __shfl_xor(ps, off, 64);
            lrow[i] = lrow[i]*alpha + ps;
            mrow[i] = nm;
            #pragma unroll
            for (int j=0;j<4;j++) o[i][j] *= alpha;
          }
          __syncthreads();
          #pragma unroll
          for (int i=0;i<4;i++)
            #pragma unroll
            for (int j=0;j<4;j++)
              KPs[tx*4+j][ty*4+i] = s[i][j];
          __syncthreads();
          #pragma unroll 8
          for (int kk = 0; kk < 64; ++kk) {
            const float4 a  = *(const float4*)&KPs[kk][ty*4];
            const float4 bb = *(const float4*)&Vs[kk][tx*4];
            const float av[4]={a.x,a.y,a.z,a.w};
            const float bv[4]={bb.x,bb.y,bb.z,bb.w};
            #pragma unroll
            for (int i=0;i<4;i++)
              #pragma unroll
              for (int j=0;j<4;j++)
                o[i][j] += av[i]*bv[j];
          }
        }
        #pragma unroll
        for (int i=0;i<4;i++){
          const int r = ty*4 + i;
          if (r < qn) {
            const float inv = 1.0f / lrow[i];
            ushort4 ov;
            ov.x = f2bf(o[i][0]*inv); ov.y = f2bf(o[i][1]*inv);
            ov.z = f2bf(o[i][2]*inv); ov.w = f2bf(o[i][3]*inv);
            *(ushort4*)(Out + ((size_t)(b*S_ + st + qt*64 + r)) * 2048 + h*HD_ + tx*4) = ov;
          }
        }
      }
    }
    const ushort4 z = {0,0,0,0};
    for (int r = max(eff, 0) + ty; r < wlen; r += 16)
      *(ushort4*)(Out + ((size_t)(b*S_ + st + r)) * 2048 + h*HD_ + tx*4) = z;
  }
}

// ---------------- launch ----------------
extern "C" void kernel_launch(void* const* d_in, const int* in_sizes, int n_in,
                              void* d_out, int out_size, void* d_ws, size_t ws_size,
                              hipStream_t stream) {
  const float* x      = (const float*)d_in[0];
  const float* ln_a_g = (const float*)d_in[1];
  const float* ln_a_b = (const float*)d_in[2];
  const float* ln_b_g = (const float*)d_in[3];
  const float* ln_b_b = (const float*)d_in[4];
  const float* Wq     = (const float*)d_in[5];
  const float* bq     = (const float*)d_in[6];
  const float* Wk     = (const float*)d_in[7];
  const float* Wv     = (const float*)d_in[8];
  const float* bv     = (const float*)d_in[9];
  const float* Wo     = (const float*)d_in[10];
  const float* bo     = (const float*)d_in[11];
  const float* Wp     = (const float*)d_in[12];
  const float* bp     = (const float*)d_in[13];
  const float* Wproj  = (const float*)d_in[14];
  const float* bproj  = (const float*)d_in[15];
  float* out = (float*)d_out;
  float* ws  = (float*)d_ws;
  ushort* wsu = (ushort*)d_ws;

  // ws layout:
  ushort* Qsp = wsu;                         // [64*1024,128] 16.8MB
  ushort* Ksp = wsu + 8388608;               // [64*1024,128] 16.8MB
  ushort* Vth = wsu + 16777216;              // [64*64,1024]  8.4MB
  ushort* Vtl = wsu + 20971520;              // [64*64,1024]  8.4MB
  ushort* B3  = (ushort*)(ws + 12582912);    // [1024,2048] bf16
  float* glo  = ws + 16777216;               // [4096,1024] globe_out
  float* loc  = ws + 20971520;               // [4096,1024] LN_a out
  float* biascat = ws + 25165824;            // [3072]
  float* mbd  = biascat + 4096;
  float* fpar = mbd + 4096;
  int*   ipar = (int*)(fpar + 8);
  ushort* Acat  = (ushort*)(ws + 25182208);  // [4096,2048] bf16
  ushort* Bqkv  = Acat + 12582912;           // [3072,2048] bf16
  ushort* Bo    = Bqkv + 9437184;            // [1024,2048] bf16
  float*  part = (float*)Acat;               // reuse after Acat dead
  ushort* A3  = wsu;                         // [4096,2048] overlays Qsp (dead)

  const dim3 blk(256);

  // one-time: allow 64KB dynamic LDS for the pipelined QKV kernel
  static int qkv_path = -1;
  if (qkv_path < 0) {
    hipError_t e = hipFuncSetAttribute(
        reinterpret_cast<const void*>(qkv4_kernel),
        hipFuncAttributeMaxDynamicSharedMemorySize, 65536);
    qkv_path = (e == hipSuccess) ? 1 : 0;
  }

  // 1) all input prep in one dispatch
  prep_kernel<<<dim3(14336), blk, 0, stream>>>(
      x, ln_a_g, ln_a_b, ln_b_g, ln_b_b, Wq, Wk, Wv, bq, bv, Wo, Wproj,
      Acat, Bqkv, biascat, loc, B3, Bo);
  // 2) QKV GEMM with fused split epilogue -> Qsp/Ksp/Vth/Vtl
  qkv4_kernel<<<dim3(24, 32), blk, 65536, stream>>>(
      Acat, Bqkv, biascat, Qsp, Ksp, Vth, Vtl);
  // 3) MFMA causal attention (epoch-balanced pairing + T5 setprio) -> Acat
  gattn_mfma<<<dim3(8, 64), blk, 0, stream>>>(Qsp, Ksp, Vth, Vtl, Acat);
  // 4) globe_out = attn · Wo^T + bo (R10: single-sync dbuf)
  mfma_gemm2<<<dim3(8, 64), blk, 0, stream>>>(Acat, Bo, bo, glo, 1024, 1024, A3);
  // 5) predictor (device-side)
  seqmean1_kernel<<<dim3(4, 8, B_), blk, 0, stream>>>(glo, part);
  seqmean2_kernel<<<dim3(4, B_), blk, 0, stream>>>(part, mbd);
  predictor_kernel<<<dim3(1), blk, 0, stream>>>(mbd, Wp, bp, fpar, ipar);
  // 6) local attention -> A3[:, 0:1024] bf16 (self-zeroing)
  lattn_kernel<<<dim3(64, B_*H_), blk, 0, stream>>>(loc, A3, ipar, fpar);
  // 7) out = A3 · B3^T + bproj (R10: single-sync dbuf)
  mfma_gemm<<<dim3(8, 64), blk, 0, stream>>>(A3, B3, bproj, out, 2048, 1024);
}

// Round 12
// 401.181 us; speedup vs baseline: 1.0576x; 1.0292x over previous
//
#include <hip/hip_runtime.h>
#include <math.h>

#define B_ 4
#define S_ 1024
#define D_ 1024
#define H_ 16
#define HD_ 64
#define BSD_ (B_*S_*D_)

using short8 = __attribute__((ext_vector_type(8))) short;
using f32x4  = __attribute__((ext_vector_type(4))) float;

#define MFMA16(a,b,c) __builtin_amdgcn_mfma_f32_16x16x32_bf16((a),(b),(c),0,0,0)

// ---------------- bf16 helpers (RNE) ----------------
__device__ __forceinline__ ushort f2bf(float f) {
  uint u = __float_as_uint(f);
  return (ushort)((u + 0x7fffu + ((u >> 16) & 1u)) >> 16);
}
__device__ __forceinline__ float bf2f(ushort h) {
  return __uint_as_float(((uint)h) << 16);
}
__device__ __forceinline__ void split8(const float* p, short8* hi, short8* lo) {
  #pragma unroll
  for (int j = 0; j < 8; j++) {
    ushort h = f2bf(p[j]);
    (*hi)[j] = (short)h;
    (*lo)[j] = (short)f2bf(p[j] - bf2f(h));
  }
}
// async global->LDS, 16B per lane; LDS dest = wave-uniform base + lane*16
__device__ __forceinline__ void async_load16(const ushort* g, ushort* l) {
  __builtin_amdgcn_global_load_lds(
      (const __attribute__((address_space(1))) unsigned int*)g,
      (__attribute__((address_space(3))) unsigned int*)l, 16, 0, 0);
}

// ---------------- block reduce (256 threads = 4 waves) ----------------
__device__ __forceinline__ float block_reduce_sum_256(float v, float* sbuf) {
  #pragma unroll
  for (int off = 32; off > 0; off >>= 1) v += __shfl_xor(v, off, 64);
  int lane = threadIdx.x & 63, wid = threadIdx.x >> 6;
  __syncthreads();
  if (lane == 0) sbuf[wid] = v;
  __syncthreads();
  return sbuf[0] + sbuf[1] + sbuf[2] + sbuf[3];
}

__device__ __forceinline__ void split4_store(const float4 a, ushort* orow, int c, int stride) {
  ushort4 hi, lo;
  hi.x = f2bf(a.x); hi.y = f2bf(a.y); hi.z = f2bf(a.z); hi.w = f2bf(a.w);
  lo.x = f2bf(a.x - bf2f(hi.x)); lo.y = f2bf(a.y - bf2f(hi.y));
  lo.z = f2bf(a.z - bf2f(hi.z)); lo.w = f2bf(a.w - bf2f(hi.w));
  *(ushort4*)(orow + c)          = hi;
  *(ushort4*)(orow + stride + c) = lo;
}

// ---------------- fused prep: all input-side transforms in ONE dispatch ----------
__global__ __launch_bounds__(256) void prep_kernel(
    const float* __restrict__ x,
    const float* __restrict__ ln_a_g, const float* __restrict__ ln_a_b,
    const float* __restrict__ ln_b_g, const float* __restrict__ ln_b_b,
    const float* __restrict__ Wq, const float* __restrict__ Wk,
    const float* __restrict__ Wv, const float* __restrict__ bq,
    const float* __restrict__ bv, const float* __restrict__ Wo,
    const float* __restrict__ Wproj,
    ushort* __restrict__ Acat, ushort* __restrict__ Bqkv,
    float* __restrict__ biascat, float* __restrict__ loc,
    ushort* __restrict__ B3, ushort* __restrict__ Bo) {
  __shared__ float sbuf[4];
  const int bx = blockIdx.x;
  const int t = threadIdx.x;
  if (bx < 4096) {
    const int row = bx;
    const int c = t*4;
    const float* xr = x + (size_t)row * D_;
    float4 v = *(const float4*)(xr + c);
    float s = v.x + v.y + v.z + v.w;
    const float mean = block_reduce_sum_256(s, sbuf) * (1.0f/D_);
    float4 dv = make_float4(v.x-mean, v.y-mean, v.z-mean, v.w-mean);
    float sq = dv.x*dv.x + dv.y*dv.y + dv.z*dv.z + dv.w*dv.w;
    const float var = block_reduce_sum_256(sq, sbuf) * (1.0f/D_);
    const float r = rsqrtf(var + 1e-5f);
    float4 gg = *(const float4*)(ln_b_g + c);
    float4 bb = *(const float4*)(ln_b_b + c);
    float4 n;
    n.x = dv.x*r*gg.x + bb.x; n.y = dv.y*r*gg.y + bb.y;
    n.z = dv.z*r*gg.z + bb.z; n.w = dv.w*r*gg.w + bb.w;
    split4_store(n, Acat + (size_t)row*2048, c, 1024);
  } else if (bx < 7168) {
    const int idx = (bx - 4096)*256 + t;
    const int n = idx >> 8;
    const int col4 = (idx & 255) << 2;
    const float* src = (n < 1024) ? (Wq + (size_t)n*1024)
                     : (n < 2048) ? (Wk + (size_t)(n-1024)*1024)
                                  : (Wv + (size_t)(n-2048)*1024);
    const float4 a = *(const float4*)(src + col4);
    split4_store(a, Bqkv + (size_t)n*2048, col4, 1024);
    if (idx < 3072)
      biascat[idx] = (idx < 1024) ? bq[idx] : (idx < 2048) ? 0.f : bv[idx-2048];
  } else if (bx < 11264) {
    const int row = bx - 7168;
    const float* xr = x + (size_t)row * D_;
    float v[4]; float s = 0.f;
    #pragma unroll
    for (int i = 0; i < 4; i++) { v[i] = xr[t + 256*i]; s += v[i]; }
    const float mean = block_reduce_sum_256(s, sbuf) * (1.0f/D_);
    float sq = 0.f;
    #pragma unroll
    for (int i = 0; i < 4; i++) { float d = v[i]-mean; sq += d*d; }
    const float var = block_reduce_sum_256(sq, sbuf) * (1.0f/D_);
    const float r = rsqrtf(var + 1e-5f);
    float* orow = loc + (size_t)row * D_;
    #pragma unroll
    for (int i = 0; i < 4; i++) {
      int c = t + 256*i;
      orow[c] = (v[i]-mean)*r*ln_a_g[c] + ln_a_b[c];
    }
  } else if (bx < 13312) {
    const int idx = (bx - 11264)*256 + t;
    const int row = idx >> 9;
    const int col4 = (idx & 511) << 2;
    const float4 a = *(const float4*)(Wproj + (size_t)row*2048 + col4);
    ushort4 hi;
    hi.x = f2bf(a.x); hi.y = f2bf(a.y); hi.z = f2bf(a.z); hi.w = f2bf(a.w);
    *(ushort4*)(B3 + (size_t)row*2048 + col4) = hi;
  } else {
    const int idx = (bx - 13312)*256 + t;
    const int n = idx >> 8;
    const int col4 = (idx & 255) << 2;
    const float4 a = *(const float4*)(Wo + (size_t)n*1024 + col4);
    split4_store(a, Bo + (size_t)n*2048, col4, 1024);
  }
}

// =====================================================================
// 128x128 pipelined QKV GEMM (R9 single-sync + R11 fragment reuse):
// B fragments loaded once for both nh, A fragments once per mh ->
// ds_read_b128 per K-step 32 -> 16. MFMA order bit-identical.
// =====================================================================
#define BARRIER() asm volatile("s_barrier" ::: "memory")
#define VMW(n)  asm volatile("s_waitcnt vmcnt(" #n ")" ::: "memory")

#define STAGE4(k0, SBs) do { \
  _Pragma("unroll") \
  for (int i_ = 0; i_ < 2; ++i_) { \
    const int cid_ = wave*2 + i_, hl_ = cid_>>2, rs_ = cid_&3; \
    const int r0_ = (rs_>>1)*64 + (rs_&1)*16; \
    async_load16(A  + ((size_t)(bm + r0_ + lrow) << 11) + (hl_ << 10) + (k0) + sw, \
                 (SBs) + hl_*4096 + r0_*32); \
  } \
  _Pragma("unroll") \
  for (int i_ = 0; i_ < 2; ++i_) { \
    const int cid_ = wave*2 + i_, hl_ = cid_>>2, rs_ = cid_&3; \
    const int r0_ = (rs_>>1)*64 + (rs_&1)*16; \
    async_load16(Bw + ((size_t)(bn + r0_ + lrow) << 11) + (hl_ << 10) + (k0) + sw, \
                 (SBs) + 8192 + hl_*4096 + r0_*32); \
  } \
  _Pragma("unroll") \
  for (int i_ = 0; i_ < 2; ++i_) { \
    const int cid_ = wave*2 + i_, hl_ = cid_>>2, rs_ = cid_&3; \
    const int r1_ = (rs_>>1)*64 + (rs_&1)*16 + 32; \
    async_load16(Bw + ((size_t)(bn + r1_ + lrow) << 11) + (hl_ << 10) + (k0) + sw, \
                 (SBs) + 8192 + hl_*4096 + r1_*32); \
  } \
  _Pragma("unroll") \
  for (int i_ = 0; i_ < 2; ++i_) { \
    const int cid_ = wave*2 + i_, hl_ = cid_>>2, rs_ = cid_&3; \
    const int r1_ = (rs_>>1)*64 + (rs_&1)*16 + 32; \
    async_load16(A  + ((size_t)(bm + r1_ + lrow) << 11) + (hl_ << 10) + (k0) + sw, \
                 (SBs) + hl_*4096 + r1_*32); \
  } \
} while (0)

// K-group g (R11): load all B frags once, stage t+1, then per-mh load A
// frags and run both quadrants. Per-acc-element MFMA chain unchanged.
#define GROUP4(g, SBc, SBs) do { \
  const int k0n_ = (((g) + 1) & 31) * 32; \
  short8 bh_[2][2], bl_[2][2]; \
  _Pragma("unroll") \
  for (int nh_ = 0; nh_ < 2; ++nh_) \
    _Pragma("unroll") \
    for (int n2_ = 0; n2_ < 2; ++n2_) { \
      const int ro_ = (wn*64 + nh_*32 + n2_*16 + lm)*32 + rsw; \
      bh_[nh_][n2_] = *(const short8*)&(SBc)[8192 + ro_]; \
      bl_[nh_][n2_] = *(const short8*)&(SBc)[12288 + ro_]; } \
  STAGE4(k0n_, (SBs)); \
  _Pragma("unroll") \
  for (int mh_ = 0; mh_ < 2; ++mh_) { \
    short8 ah_[2], al_[2]; \
    _Pragma("unroll") \
    for (int m4_ = 0; m4_ < 2; ++m4_) { \
      const int ro_ = (wm*64 + mh_*32 + m4_*16 + lm)*32 + rsw; \
      ah_[m4_] = *(const short8*)&(SBc)[ro_]; \
      al_[m4_] = *(const short8*)&(SBc)[4096 + ro_]; } \
    __builtin_amdgcn_s_setprio(1); \
    _Pragma("unroll") \
    for (int nh_ = 0; nh_ < 2; ++nh_) \
      _Pragma("unroll") \
      for (int m4_ = 0; m4_ < 2; ++m4_) \
        _Pragma("unroll") \
        for (int n2_ = 0; n2_ < 2; ++n2_) { \
          f32x4 t_ = acc[mh_*2+m4_][nh_*2+n2_]; \
          t_ = MFMA16(ah_[m4_], bh_[nh_][n2_], t_); \
          t_ = MFMA16(al_[m4_], bh_[nh_][n2_], t_); \
          t_ = MFMA16(ah_[m4_], bl_[nh_][n2_], t_); \
          acc[mh_*2+m4_][nh_*2+n2_] = t_; } \
    __builtin_amdgcn_s_setprio(0); \
  } \
  VMW(0); \
  BARRIER(); \
} while (0)

__global__ __launch_bounds__(256, 2) void qkv4_kernel(
    const ushort* __restrict__ A, const ushort* __restrict__ Bw,
    const float* __restrict__ bias,
    ushort* __restrict__ Qsp, ushort* __restrict__ Ksp,
    ushort* __restrict__ Vth, ushort* __restrict__ Vtl) {
  extern __shared__ __align__(16) ushort smem[];   // 2 slots x 32KB
  const int tid = threadIdx.x;
  const int bm = blockIdx.y * 128, bn = blockIdx.x * 128;
  const int wave = tid >> 6, lane = tid & 63;
  const int wm = wave >> 1, wn = wave & 1;
  const int lm = lane & 15, q = lane >> 4;
  const int lrow = lane >> 2;
  const int sw = (((lane & 3) ^ ((lane >> 3) & 3)) << 3);
  const int rsw = ((q ^ ((lm >> 1) & 3)) << 3);

  f32x4 acc[4][4];
  #pragma unroll
  for (int i = 0; i < 4; i++)
    #pragma unroll
    for (int j = 0; j < 4; j++)
      acc[i][j] = (f32x4){0.f,0.f,0.f,0.f};

  STAGE4(0, smem);
  VMW(0); BARRIER();

  #pragma unroll 1
  for (int g = 0; g < 32; g += 2) {
    GROUP4(g,     smem,         smem + 16384);
    GROUP4(g + 1, smem + 16384, smem);
  }
  VMW(0);
  __syncthreads();

  const int b = bm >> 10, s0 = bm & 1023;
  if (blockIdx.x < 16) {
    ushort* dst = (blockIdx.x < 8) ? Qsp : Ksp;
    #pragma unroll
    for (int mt = 0; mt < 4; mt++) {
      #pragma unroll
      for (int nt = 0; nt < 4; nt++) {
        const int n = bn + wn*64 + nt*16 + lm;
        const int h = (n >> 6) & 15;
        const int d = nt*16 + lm;
        const float bb = bias[n];
        #pragma unroll
        for (int reg = 0; reg < 4; reg++) {
          const int s = s0 + wm*64 + mt*16 + q*4 + reg;
          const float val = acc[mt][nt][reg] + bb;
          const ushort hi = f2bf(val);
          const ushort lo = f2bf(val - bf2f(hi));
          ushort* rp = dst + ((size_t)((b*16 + h)*1024 + s))*128;
          rp[d] = hi; rp[64 + d] = lo;
        }
      }
    }
  } else {
    ushort* Th = smem;            // [64][136] ushorts
    ushort* Tl = smem + 8704;
    #pragma unroll
    for (int c = 0; c < 2; c++) {
      __syncthreads();
      if (wn == c) {
        #pragma unroll
        for (int mt = 0; mt < 4; mt++)
          #pragma unroll
          for (int nt = 0; nt < 4; nt++) {
            const int nl = nt*16 + lm;
            const float bb = bias[bn + c*64 + nl];
            #pragma unroll
            for (int reg = 0; reg < 4; reg++) {
              const int sl = wm*64 + mt*16 + q*4 + reg;
              const float val = acc[mt][nt][reg] + bb;
              const ushort hi = f2bf(val);
              const ushort lo = f2bf(val - bf2f(hi));
              Th[nl*136 + sl] = hi;
              Tl[nl*136 + sl] = lo;
            }
          }
      }
      __syncthreads();
      const int nl = tid >> 2, s32 = (tid & 3)*32;
      const int h = ((bn - 2048 + c*64) >> 6) & 15;
      const size_t drow = ((size_t)((b*16 + h)*64 + nl))*1024 + s0 + s32;
      #pragma unroll
      for (int j = 0; j < 4; j++) {
        *(short8*)(Vth + drow + j*8) = *(const short8*)&Th[nl*136 + s32 + j*8];
        *(short8*)(Vtl + drow + j*8) = *(const short8*)&Tl[nl*136 + s32 + j*8];
      }
    }
  }
}

// ------- dual-panel bf16x3 MFMA GEMM, 64x128 tile, R10 single-sync dbuf ----------
#define G2_STAGE(k0, slot) do { \
  _Pragma("unroll") \
  for (int i_ = 0; i_ < 6; ++i_) \
    async_load16(gsrc[i_] + (k0), &S2[slot][loff[i_]]); \
} while (0)

#define G2_STEP(slot) do { \
  const ushort* P_ = &S2[slot][0]; \
  short8 ah_[4], al_[4], bh_[2], bl_[2]; \
  _Pragma("unroll") \
  for (int mt_ = 0; mt_ < 4; mt_++) { \
    ah_[mt_] = *(const short8*)&P_[aoff + mt_*512]; \
    al_[mt_] = *(const short8*)&P_[2048 + aoff + mt_*512]; } \
  _Pragma("unroll") \
  for (int nt_ = 0; nt_ < 2; nt_++) { \
    bh_[nt_] = *(const short8*)&P_[4096 + boff + nt_*512]; \
    bl_[nt_] = *(const short8*)&P_[8192 + boff + nt_*512]; } \
  __builtin_amdgcn_s_setprio(1); \
  _Pragma("unroll") \
  for (int mt_ = 0; mt_ < 4; mt_++) \
    _Pragma("unroll") \
    for (int nt_ = 0; nt_ < 2; nt_++) { \
      f32x4 a_ = acc[mt_][nt_]; \
      a_ = MFMA16(ah_[mt_], bh_[nt_], a_); \
      a_ = MFMA16(al_[mt_], bh_[nt_], a_); \
      a_ = MFMA16(ah_[mt_], bl_[nt_], a_); \
      acc[mt_][nt_] = a_; } \
  __builtin_amdgcn_s_setprio(0); \
} while (0)

__global__ __launch_bounds__(256) void mfma_gemm2(
    const ushort* __restrict__ A, const ushort* __restrict__ Bw,
    const float* __restrict__ bias, float* __restrict__ C,
    int Kh, int ldc, ushort* __restrict__ aux) {
  __shared__ __align__(16) ushort S2[2][12288];   // 48KB total
  const int lda = 2*Kh;
  const int tid = threadIdx.x;
  const int bm = blockIdx.y * 64, bn = blockIdx.x * 128;
  const int wave = tid >> 6, lane = tid & 63;
  const int lm = lane & 15, q = lane >> 4;
  const int lrow = lane >> 2;
  const int sw = (((lane & 3) ^ ((lane >> 3) & 3)) << 3);

  f32x4 acc[4][2];
  #pragma unroll
  for (int i = 0; i < 4; i++)
    #pragma unroll
    for (int j = 0; j < 2; j++)
      acc[i][j] = (f32x4){0.f,0.f,0.f,0.f};

  const ushort* gsrc[6];
  int loff[6];
  #pragma unroll
  for (int i = 0; i < 6; i++) {
    const int s = wave*6 + i;
    const ushort* gp; int lp;
    if (s < 4)       { gp = A  + (size_t)(bm + s*16 + lrow)*lda + sw;           lp = (s*16)*32; }
    else if (s < 8)  { gp = A  + (size_t)(bm + (s-4)*16 + lrow)*lda + Kh + sw;  lp = 2048 + ((s-4)*16)*32; }
    else if (s < 16) { gp = Bw + (size_t)(bn + (s-8)*16 + lrow)*lda + sw;       lp = 4096 + ((s-8)*16)*32; }
    else             { gp = Bw + (size_t)(bn + (s-16)*16 + lrow)*lda + Kh + sw; lp = 8192 + ((s-16)*16)*32; }
    gsrc[i] = gp; loff[i] = lp;
  }
  const int rsw = ((q ^ ((lm >> 1) & 3)) << 3);
  const int aoff = lm*32 + rsw;
  const int boff = (wave*32 + lm)*32 + rsw;

  G2_STAGE(0, 0);
  VMW(0); BARRIER();

  #pragma unroll 1
  for (int k0 = 0; k0 < Kh; k0 += 64) {
    if (k0 + 32 < Kh) G2_STAGE(k0 + 32, 1);
    G2_STEP(0);
    VMW(0); BARRIER();
    if (k0 + 64 < Kh) G2_STAGE(k0 + 64, 0);
    G2_STEP(1);
    VMW(0); BARRIER();
  }

  #pragma unroll
  for (int mt = 0; mt < 4; mt++) {
    #pragma unroll
    for (int nt = 0; nt < 2; nt++) {
      const int n = bn + wave*32 + nt*16 + lm;
      const float bb = bias ? bias[n] : 0.f;
      #pragma unroll
      for (int reg = 0; reg < 4; reg++) {
        const int m = bm + mt*16 + q*4 + reg;
        const float val = acc[mt][nt][reg] + bb;
        C[(size_t)m*ldc + n] = val;
        if (aux) aux[(size_t)m*2048 + 1024 + n] = f2bf(val);
      }
    }
  }
}

// ---------- plain bf16 MFMA GEMM, 64x128 tile, R10 single-sync dbuf --------------
#define G1_STAGE(k0, slot) do { \
  _Pragma("unroll") \
  for (int i_ = 0; i_ < 3; ++i_) \
    async_load16(gsrc[i_] + (k0), &S1[slot][loff[i_]]); \
} while (0)

#define G1_STEP(slot) do { \
  const ushort* P_ = &S1[slot][0]; \
  short8 af_[4], bf_[2]; \
  _Pragma("unroll") \
  for (int mt_ = 0; mt_ < 4; mt_++) af_[mt_] = *(const short8*)&P_[aoff + mt_*512]; \
  _Pragma("unroll") \
  for (int nt_ = 0; nt_ < 2; nt_++) bf_[nt_] = *(const short8*)&P_[2048 + boff + nt_*512]; \
  __builtin_amdgcn_s_setprio(1); \
  _Pragma("unroll") \
  for (int mt_ = 0; mt_ < 4; mt_++) \
    _Pragma("unroll") \
    for (int nt_ = 0; nt_ < 2; nt_++) \
      acc[mt_][nt_] = MFMA16(af_[mt_], bf_[nt_], acc[mt_][nt_]); \
  __builtin_amdgcn_s_setprio(0); \
} while (0)

__global__ __launch_bounds__(256) void mfma_gemm(
    const ushort* __restrict__ A, const ushort* __restrict__ Bw,
    const float* __restrict__ bias, float* __restrict__ C,
    int K, int ldc) {
  __shared__ __align__(16) ushort S1[2][6144];    // 24KB total
  const int tid = threadIdx.x;
  const int bm = blockIdx.y * 64, bn = blockIdx.x * 128;
  const int wave = tid >> 6, lane = tid & 63;
  const int lm = lane & 15, q = lane >> 4;
  const int lrow = lane >> 2;
  const int sw = (((lane & 3) ^ ((lane >> 3) & 3)) << 3);

  f32x4 acc[4][2];
  #pragma unroll
  for (int i = 0; i < 4; i++)
    #pragma unroll
    for (int j = 0; j < 2; j++)
      acc[i][j] = (f32x4){0.f,0.f,0.f,0.f};

  const ushort* gsrc[3];
  int loff[3];
  #pragma unroll
  for (int i = 0; i < 3; i++) {
    const int s = wave*3 + i;
    const ushort* gp; int lp;
    if (s < 4) { gp = A  + (size_t)(bm + s*16 + lrow)*K + sw;     lp = (s*16)*32; }
    else       { gp = Bw + (size_t)(bn + (s-4)*16 + lrow)*K + sw; lp = 2048 + ((s-4)*16)*32; }
    gsrc[i] = gp; loff[i] = lp;
  }
  const int rsw = ((q ^ ((lm >> 1) & 3)) << 3);
  const int aoff = lm*32 + rsw;
  const int boff = (wave*32 + lm)*32 + rsw;

  G1_STAGE(0, 0);
  VMW(0); BARRIER();

  #pragma unroll 1
  for (int k0 = 0; k0 < K; k0 += 64) {
    if (k0 + 32 < K) G1_STAGE(k0 + 32, 1);
    G1_STEP(0);
    VMW(0); BARRIER();
    if (k0 + 64 < K) G1_STAGE(k0 + 64, 0);
    G1_STEP(1);
    VMW(0); BARRIER();
  }

  #pragma unroll
  for (int mt = 0; mt < 4; mt++) {
    #pragma unroll
    for (int nt = 0; nt < 2; nt++) {
      const int n = bn + wave*32 + nt*16 + lm;
      const float bb = bias ? bias[n] : 0.f;
      #pragma unroll
      for (int reg = 0; reg < 4; reg++) {
        const int m = bm + mt*16 + q*4 + reg;
        C[(size_t)m*ldc + n] = acc[mt][nt][reg] + bb;
      }
    }
  }
}

// ---- one q-tile x k-tile attention unit (scores -> softmax -> PV) ----
// T5: setprio(1) around both MFMA clusters (R8 win).
__device__ __forceinline__ void attn_unit(
    int qt, int kt, int w, int lm, int q,
    const short8 qh[2], const short8 ql[2],
    const ushort* Kc, const ushort* Vc, float* Pf,
    f32x4 of[4], float mst[4], float lst[4]) {
  f32x4 sS[4];
  __builtin_amdgcn_s_setprio(1);
  #pragma unroll
  for (int nt = 0; nt < 4; nt++) {
    const ushort* kr = &Kc[(nt*16 + lm)*136 + q*8];
    const short8 kh0 = *(const short8*)(kr);
    const short8 kh1 = *(const short8*)(kr + 32);
    const short8 kl0 = *(const short8*)(kr + 64);
    const short8 kl1 = *(const short8*)(kr + 96);
    f32x4 a = (f32x4){0.f,0.f,0.f,0.f};
    a = MFMA16(qh[0], kh0, a);
    a = MFMA16(ql[0], kh0, a);
    a = MFMA16(qh[0], kl0, a);
    a = MFMA16(qh[1], kh1, a);
    a = MFMA16(ql[1], kh1, a);
    a = MFMA16(qh[1], kl1, a);
    sS[nt] = a;
  }
  __builtin_amdgcn_s_setprio(0);
  const int ktbase = kt*64;
  const int qrow0 = qt*64 + w*16 + q*4;
  #pragma unroll
  for (int rm = 0; rm < 4; rm++) {
    const int qrow = qrow0 + rm;
    float v[4];
    #pragma unroll
    for (int nt = 0; nt < 4; nt++) {
      const int kcol = ktbase + nt*16 + lm;
      const float x = sS[nt][rm]*0.125f;
      v[nt] = (kcol <= qrow) ? x : -INFINITY;
    }
    float tm = fmaxf(fmaxf(v[0],v[1]), fmaxf(v[2],v[3]));
    #pragma unroll
    for (int off = 1; off < 16; off <<= 1) tm = fmaxf(tm, __shfl_xor(tm, off, 64));
    const float nm = fmaxf(mst[rm], tm);
    const float alpha = __expf(mst[rm] - nm);
    float ps = 0.f;
    #pragma unroll
    for (int nt = 0; nt < 4; nt++) {
      float p = __expf(v[nt] - nm);
      sS[nt][rm] = p;
      ps += p;
    }
    #pragma unroll
    for (int off = 1; off < 16; off <<= 1) ps += __shfl_xor(ps, off, 64);
    lst[rm] = lst[rm]*alpha + ps;
    mst[rm] = nm;
    #pragma unroll
    for (int nt = 0; nt < 4; nt++) of[nt][rm] *= alpha;
  }
  #pragma unroll
  for (int rm = 0; rm < 4; rm++)
    #pragma unroll
    for (int nt = 0; nt < 4; nt++)
      Pf[(w*16 + q*4 + rm)*66 + nt*16 + lm] = sS[nt][rm];
  short8 ph[2], pl[2];
  {
    const float* prow = &Pf[(w*16 + lm)*66];
    float pv[16];
    *(float4*)&pv[0]  = *(const float4*)(prow + q*8);
    *(float4*)&pv[4]  = *(const float4*)(prow + q*8 + 4);
    *(float4*)&pv[8]  = *(const float4*)(prow + 32 + q*8);
    *(float4*)&pv[12] = *(const float4*)(prow + 32 + q*8 + 4);
    split8(&pv[0], &ph[0], &pl[0]);
    split8(&pv[8], &ph[1], &pl[1]);
  }
  __builtin_amdgcn_s_setprio(1);
  #pragma unroll
  for (int nt = 0; nt < 4; nt++) {
    const ushort* vr = &Vc[(nt*16 + lm)*136 + q*8];
    const short8 vh0 = *(const short8*)(vr);
    const short8 vh1 = *(const short8*)(vr + 32);
    const short8 vl0 = *(const short8*)(vr + 64);
    const short8 vl1 = *(const short8*)(vr + 96);
    f32x4 a = of[nt];
    a = MFMA16(ph[0], vh0, a);
    a = MFMA16(pl[0], vh0, a);
    a = MFMA16(ph[0], vl0, a);
    a = MFMA16(ph[1], vh1, a);
    a = MFMA16(pl[1], vh1, a);
    a = MFMA16(ph[1], vl1, a);
    of[nt] = a;
  }
  __builtin_amdgcn_s_setprio(0);
}

// ---- MFMA causal flash attention: dual q-tile, shared K/V staging ----
// XCD-aware epoch balancing (R7 win): per-CU epoch sum = 25, constant.
__global__ __launch_bounds__(256) void gattn_mfma(
    const ushort* __restrict__ Qsp, const ushort* __restrict__ Ksp,
    const ushort* __restrict__ Vth, const ushort* __restrict__ Vtl,
    ushort* __restrict__ Aout) {
  __shared__ __align__(16) ushort Kc[64*136];
  __shared__ __align__(16) ushort Vc[64*136];
  __shared__ __align__(16) float  Pf[64*66];
  const int bh = blockIdx.y;
  const int b = bh >> 4, h = bh & 15;
  const int tid = threadIdx.x;
  const int w = tid >> 6, lane = tid & 63;
  const int lm = lane & 15, q = lane >> 4;
  const ushort* Qb_ = Qsp + (size_t)bh * (1024*128);
  const ushort* Kb_ = Ksp + (size_t)bh * (1024*128);
  const ushort* Vhb = Vth + (size_t)bh * (64*1024);
  const ushort* Vlb = Vtl + (size_t)bh * (64*1024);
  const int half = (bh >> 5) & 1;
  const int qtA = half ? (8 + (int)blockIdx.x) : (15 - (int)blockIdx.x);
  const int qtB = half ? (7 - (int)blockIdx.x) : (int)blockIdx.x;

  short8 qhA[2], qlA[2], qhB[2], qlB[2];
  {
    const ushort* qr = Qb_ + (size_t)(qtA*64 + w*16 + lm)*128 + q*8;
    qhA[0] = *(const short8*)(qr);
    qhA[1] = *(const short8*)(qr + 32);
    qlA[0] = *(const short8*)(qr + 64);
    qlA[1] = *(const short8*)(qr + 96);
    const ushort* qr2 = Qb_ + (size_t)(qtB*64 + w*16 + lm)*128 + q*8;
    qhB[0] = *(const short8*)(qr2);
    qhB[1] = *(const short8*)(qr2 + 32);
    qlB[0] = *(const short8*)(qr2 + 64);
    qlB[1] = *(const short8*)(qr2 + 96);
  }
  f32x4 ofA[4], ofB[4];
  float mstA[4], lstA[4], mstB[4], lstB[4];
  #pragma unroll
  for (int nt = 0; nt < 4; nt++) {
    ofA[nt] = (f32x4){0.f,0.f,0.f,0.f};
    ofB[nt] = (f32x4){0.f,0.f,0.f,0.f};
  }
  #pragma unroll
  for (int rm = 0; rm < 4; rm++) {
    mstA[rm] = -INFINITY; lstA[rm] = 0.f;
    mstB[rm] = -INFINITY; lstB[rm] = 0.f;
  }

  for (int kt = 0; kt <= qtA; ++kt) {
    __syncthreads();
    #pragma unroll
    for (int i = 0; i < 4; i++) {
      const int slot = i*256 + tid;
      const int row = slot >> 4, c8 = slot & 15;
      *(float4*)&Kc[row*136 + c8*8] =
          *(const float4*)(Kb_ + (size_t)(kt*64 + row)*128 + c8*8);
      const ushort* vsrc = ((c8 < 8) ? Vhb : Vlb) + (size_t)row*1024 + kt*64 + (c8&7)*8;
      *(float4*)&Vc[row*136 + c8*8] = *(const float4*)vsrc;
    }
    __syncthreads();
    attn_unit(qtA, kt, w, lm, q, qhA, qlA, Kc, Vc, Pf, ofA, mstA, lstA);
    if (kt <= qtB)
      attn_unit(qtB, kt, w, lm, q, qhB, qlB, Kc, Vc, Pf, ofB, mstB, lstB);
  }

  #pragma unroll
  for (int rm = 0; rm < 4; rm++) {
    const float invA = 1.0f / lstA[rm];
    const int sA = qtA*64 + w*16 + q*4 + rm;
    ushort* arow = Aout + ((size_t)(b*1024 + sA))*2048 + h*64;
    #pragma unroll
    for (int nt = 0; nt < 4; nt++) {
      const float val = ofA[nt][rm] * invA;
      const ushort hi = f2bf(val);
      arow[nt*16 + lm] = hi;
      arow[1024 + nt*16 + lm] = f2bf(val - bf2f(hi));
    }
    const float invB = 1.0f / lstB[rm];
    const int sB = qtB*64 + w*16 + q*4 + rm;
    ushort* brow = Aout + ((size_t)(b*1024 + sB))*2048 + h*64;
    #pragma unroll
    for (int nt = 0; nt < 4; nt++) {
      const float val = ofB[nt][rm] * invB;
      const ushort hi = f2bf(val);
      brow[nt*16 + lm] = hi;
      brow[1024 + nt*16 + lm] = f2bf(val - bf2f(hi));
    }
  }
}

// ---------------- seq-mean, 2-stage deterministic ----------------
__global__ __launch_bounds__(256) void seqmean1_kernel(const float* __restrict__ g,
                                                       float* __restrict__ part) {
  const int d = blockIdx.x*256 + threadIdx.x;
  const int sc = blockIdx.y;
  const int b = blockIdx.z;
  const float* p = g + ((size_t)b*S_ + sc*128)*D_ + d;
  float s = 0.f;
  #pragma unroll 4
  for (int i = 0; i < 128; i++) s += p[(size_t)i*D_];
  part[((size_t)(b*8 + sc))*D_ + d] = s;
}
__global__ __launch_bounds__(256) void seqmean2_kernel(const float* __restrict__ part,
                                                       float* __restrict__ mbd) {
  const int d = blockIdx.x*256 + threadIdx.x;
  const int b = blockIdx.y;
  float s = 0.f;
  #pragma unroll
  for (int i = 0; i < 8; i++) s += part[((size_t)(b*8 + i))*D_ + d];
  mbd[b*D_ + d] = s * (1.0f/S_);
}

// ---------------- predictor ----------------
__global__ __launch_bounds__(256) void predictor_kernel(
    const float* __restrict__ mbd, const float* __restrict__ Wp,
    const float* __restrict__ bp, float* __restrict__ fpar, int* __restrict__ ipar) {
  __shared__ float sbuf[4];
  __shared__ float sdots[4];
  const int tid = threadIdx.x;
  for (int b = 0; b < 4; b++) {
    float psum = 0.f;
    for (int d = tid; d < D_; d += 256) psum += mbd[b*D_ + d]*Wp[d];
    float tot = block_reduce_sum_256(psum, sbuf);
    if (tid == 0) sdots[b] = tot;
  }
  __syncthreads();
  if (tid == 0) {
    float smv = 0.f;
    for (int b = 0; b < 4; b++) {
      float z = sdots[b] + bp[0];
      smv += 1.0f/(1.0f + expf(-z));
    }
    smv *= 0.25f;
    int win = max(1, (int)(256.0f*smv));
    int span_len = max(1, (int)(512.0f*smv));
    int local_max = min(512, min(span_len, win));
    float temp = 1.0f + 0.01f*(1.0f - smv);
    int n_win = (S_ + win - 1)/win;
    fpar[0] = smv; fpar[1] = temp;
    ipar[0] = win; ipar[1] = span_len; ipar[2] = local_max; ipar[3] = n_win;
  }
}

// -------- dynamic sliding-window span attention (fp32 -> bf16 out, self-zeroing) --
#define LDP 68
__global__ __launch_bounds__(256) void lattn_kernel(
    const float* __restrict__ Lc, ushort* __restrict__ Out,
    const int* __restrict__ ip, const float* __restrict__ fpp) {
  __shared__ __align__(16) float Qs[HD_][LDP];
  __shared__ __align__(16) float KPs[64][LDP];
  __shared__ __align__(16) float Vs[64][LDP];
  const int n_win = ip[3];
  const int win = ip[0], span_len = ip[1], local_max = ip[2];
  const float sm = fpp[0], temp = fpp[1];
  const int bh = blockIdx.y;
  const int b = bh >> 4, h = bh & 15;
  const int tid = threadIdx.x;
  const int tx = tid & 15, ty = tid >> 4;
  const float sc = 0.35355339059327373f / temp;
  for (int w = blockIdx.x; w < n_win; w += gridDim.x) {
    const int st = w * win;
    const int en = min(st + win, S_); const int wlen = en - st;
    const int ks = max(0, st - span_len + win);
    const int ke = min(st + span_len, S_); const int klen = ke - ks;
    int eff = (int)((double)wlen * (double)sm);
    eff = min(min(eff, wlen), min(klen, local_max));
    if (eff > 0) {
      const int nt = (eff + 63) >> 6;
      for (int qt = 0; qt < nt; ++qt) {
        const int qn = min(64, eff - qt*64);
        __syncthreads();
        #pragma unroll
        for (int c = 0; c < 4; c++) {
          int f = tid + c*256;
          int r = f >> 4;
          int dc = (f & 15) << 2;
          float4 q4 = make_float4(0.f,0.f,0.f,0.f);
          if (r < qn) q4 = *(const float4*)(Lc + ((size_t)(b*S_ + st + qt*64 + r)) * D_ + h*HD_ + dc);
          Qs[dc+0][r]=q4.x; Qs[dc+1][r]=q4.y; Qs[dc+2][r]=q4.z; Qs[dc+3][r]=q4.w;
        }
        float o[4][4] = {{0.f,0.f,0.f,0.f},{0.f,0.f,0.f,0.f},{0.f,0.f,0.f,0.f},{0.f,0.f,0.f,0.f}};
        float mrow[4], lrow[4];
        #pragma unroll
        for (int i=0;i<4;i++){ mrow[i] = -INFINITY; lrow[i] = 0.f; }
        for (int kt = 0; kt < nt; ++kt) {
          const int kn = min(64, eff - kt*64);
          __syncthreads();
          #pragma unroll
          for (int c = 0; c < 4; c++) {
            int f = tid + c*256;
            int r = f >> 4;
            int dc = (f & 15) << 2;
            float4 k4 = make_float4(0.f,0.f,0.f,0.f);
            if (r < kn) k4 = *(const float4*)(Lc + ((size_t)(b*S_ + ks + kt*64 + r)) * D_ + h*HD_ + dc);
            KPs[dc+0][r]=k4.x; KPs[dc+1][r]=k4.y; KPs[dc+2][r]=k4.z; KPs[dc+3][r]=k4.w;
            *(float4*)&Vs[r][dc] = k4;
          }
          __syncthreads();
          float s[4][4] = {{0.f,0.f,0.f,0.f},{0.f,0.f,0.f,0.f},{0.f,0.f,0.f,0.f},{0.f,0.f,0.f,0.f}};
          #pragma unroll 8
          for (int d = 0; d < HD_; ++d) {
            const float4 a  = *(const float4*)&Qs[d][ty*4];
            const float4 bb = *(const float4*)&KPs[d][tx*4];
            const float av[4]={a.x,a.y,a.z,a.w};
            const float bv[4]={bb.x,bb.y,bb.z,bb.w};
            #pragma unroll
            for (int i=0;i<4;i++)
              #pragma unroll
              for (int j=0;j<4;j++)
                s[i][j] += av[i]*bv[j];
          }
          #pragma unroll
          for (int i=0;i<4;i++) {
            #pragma unroll
            for (int j=0;j<4;j++) {
              float lg = s[i][j]*sc;
              if (kt*64 + tx*4 + j >= eff) lg = -INFINITY;
              s[i][j] = lg;
            }
          }
          #pragma unroll
          for (int i=0;i<4;i++) {
            float tm = fmaxf(fmaxf(s[i][0],s[i][1]), fmaxf(s[i][2],s[i][3]));
            #pragma unroll
            for (int off=1; off<16; off<<=1) tm = fmaxf(tm, __shfl_xor(tm, off, 64));
            const float nm = fmaxf(mrow[i], tm);
            const float alpha = __expf(mrow[i]-nm);
            float ps = 0.f;
            #pragma unroll
            for (int j=0;j<4;j++){ float p = __expf(s[i][j]-nm); s[i][j]=p; ps += p; }
            #pragma unroll
            for (int off=1; off<16; off<<=1) ps += __shfl_xor(ps, off, 64);
            lrow[i] = lrow[i]*alpha + ps;
            mrow[i] = nm;
            #pragma unroll
            for (int j=0;j<4;j++) o[i][j] *= alpha;
          }
          __syncthreads();
          #pragma unroll
          for (int i=0;i<4;i++)
            #pragma unroll
            for (int j=0;j<4;j++)
              KPs[tx*4+j][ty*4+i] = s[i][j];
          __syncthreads();
          #pragma unroll 8
          for (int kk = 0; kk < 64; ++kk) {
            const float4 a  = *(const float4*)&KPs[kk][ty*4];
            const float4 bb = *(const float4*)&Vs[kk][tx*4];
            const float av[4]={a.x,a.y,a.z,a.w};
            const float bv[4]={bb.x,bb.y,bb.z,bb.w};
            #pragma unroll
            for (int i=0;i<4;i++)
              #pragma unroll
              for (int j=0;j<4;j++)
                o[i][j] += av[i]*bv[j];
          }
        }
        #pragma unroll
        for (int i=0;i<4;i++){
          const int r = ty*4 + i;
          if (r < qn) {
            const float inv = 1.0f / lrow[i];
            ushort4 ov;
            ov.x = f2bf(o[i][0]*inv); ov.y = f2bf(o[i][1]*inv);
            ov.z = f2bf(o[i][2]*inv); ov.w = f2bf(o[i][3]*inv);
            *(ushort4*)(Out + ((size_t)(b*S_ + st + qt*64 + r)) * 2048 + h*HD_ + tx*4) = ov;
          }
        }
      }
    }
    const ushort4 z = {0,0,0,0};
    for (int r = max(eff, 0) + ty; r < wlen; r += 16)
      *(ushort4*)(Out + ((size_t)(b*S_ + st + r)) * 2048 + h*HD_ + tx*4) = z;
  }
}

// ---------------- launch ----------------
extern "C" void kernel_launch(void* const* d_in, const int* in_sizes, int n_in,
                              void* d_out, int out_size, void* d_ws, size_t ws_size,
                              hipStream_t stream) {
  const float* x      = (const float*)d_in[0];
  const float* ln_a_g = (const float*)d_in[1];
  const float* ln_a_b = (const float*)d_in[2];
  const float* ln_b_g = (const float*)d_in[3];
  const float* ln_b_b = (const float*)d_in[4];
  const float* Wq     = (const float*)d_in[5];
  const float* bq     = (const float*)d_in[6];
  const float* Wk     = (const float*)d_in[7];
  const float* Wv     = (const float*)d_in[8];
  const float* bv     = (const float*)d_in[9];
  const float* Wo     = (const float*)d_in[10];
  const float* bo     = (const float*)d_in[11];
  const float* Wp     = (const float*)d_in[12];
  const float* bp     = (const float*)d_in[13];
  const float* Wproj  = (const float*)d_in[14];
  const float* bproj  = (const float*)d_in[15];
  float* out = (float*)d_out;
  float* ws  = (float*)d_ws;
  ushort* wsu = (ushort*)d_ws;

  // ws layout:
  ushort* Qsp = wsu;                         // [64*1024,128] 16.8MB
  ushort* Ksp = wsu + 8388608;               // [64*1024,128] 16.8MB
  ushort* Vth = wsu + 16777216;              // [64*64,1024]  8.4MB
  ushort* Vtl = wsu + 20971520;              // [64*64,1024]  8.4MB
  ushort* B3  = (ushort*)(ws + 12582912);    // [1024,2048] bf16
  float* glo  = ws + 16777216;               // [4096,1024] globe_out
  float* loc  = ws + 20971520;               // [4096,1024] LN_a out
  float* biascat = ws + 25165824;            // [3072]
  float* mbd  = biascat + 4096;
  float* fpar = mbd + 4096;
  int*   ipar = (int*)(fpar + 8);
  ushort* Acat  = (ushort*)(ws + 25182208);  // [4096,2048] bf16
  ushort* Bqkv  = Acat + 12582912;           // [3072,2048] bf16
  ushort* Bo    = Bqkv + 9437184;            // [1024,2048] bf16
  float*  part = (float*)Acat;               // reuse after Acat dead
  ushort* A3  = wsu;                         // [4096,2048] overlays Qsp (dead)

  const dim3 blk(256);

  // one-time: allow 64KB dynamic LDS for the pipelined QKV kernel
  static int qkv_path = -1;
  if (qkv_path < 0) {
    hipError_t e = hipFuncSetAttribute(
        reinterpret_cast<const void*>(qkv4_kernel),
        hipFuncAttributeMaxDynamicSharedMemorySize, 65536);
    qkv_path = (e == hipSuccess) ? 1 : 0;
  }

  // 1) all input prep in one dispatch
  prep_kernel<<<dim3(14336), blk, 0, stream>>>(
      x, ln_a_g, ln_a_b, ln_b_g, ln_b_b, Wq, Wk, Wv, bq, bv, Wo, Wproj,
      Acat, Bqkv, biascat, loc, B3, Bo);
  // 2) QKV GEMM with fused split epilogue -> Qsp/Ksp/Vth/Vtl
  qkv4_kernel<<<dim3(24, 32), blk, 65536, stream>>>(
      Acat, Bqkv, biascat, Qsp, Ksp, Vth, Vtl);
  // 3) MFMA causal attention (epoch-balanced pairing + T5 setprio) -> Acat
  gattn_mfma<<<dim3(8, 64), blk, 0, stream>>>(Qsp, Ksp, Vth, Vtl, Acat);
  // 4) globe_out = attn · Wo^T + bo (R10: single-sync dbuf)
  mfma_gemm2<<<dim3(8, 64), blk, 0, stream>>>(Acat, Bo, bo, glo, 1024, 1024, A3);
  // 5) predictor (device-side)
  seqmean1_kernel<<<dim3(4, 8, B_), blk, 0, stream>>>(glo, part);
  seqmean2_kernel<<<dim3(4, B_), blk, 0, stream>>>(part, mbd);
  predictor_kernel<<<dim3(1), blk, 0, stream>>>(mbd, Wp, bp, fpar, ipar);
  // 6) local attention -> A3[:, 0:1024] bf16 (self-zeroing)
  lattn_kernel<<<dim3(64, B_*H_), blk, 0, stream>>>(loc, A3, ipar, fpar);
  // 7) out = A3 · B3^T + bproj (R10: single-sync dbuf)
  mfma_gemm<<<dim3(8, 64), blk, 0, stream>>>(A3, B3, bproj, out, 2048, 1024);
}